// Round 8
// baseline (134.217 us; speedup 1.0000x reference)
//
#include <hip/hip_runtime.h>
#include <hip/hip_bf16.h>
#include <math.h>

#define BATCH  4
#define SEQ    2048
#define DMODEL 256
#define NH     8
#define DH     32
#define MTOT   (BATCH*SEQ)   // 8192
// Q is pre-scaled by 256^-0.5 * log2(e) so attention uses p = exp2(q.k) raw.
#define QSCALE 0.09016844005556021f

typedef short  bf16x8 __attribute__((ext_vector_type(8)));
typedef float  f32x4  __attribute__((ext_vector_type(4)));

static __device__ __forceinline__ ushort f2bf(float f) {
    __hip_bfloat16 h = __float2bfloat16(f);
    return __builtin_bit_cast(ushort, h);
}
// RNE-pack two fp32 -> packed bf16x2 (low = a, high = b), software fallback.
static __device__ __forceinline__ uint rne2(float a, float b) {
    uint ua = __builtin_bit_cast(uint, a);
    uint ub = __builtin_bit_cast(uint, b);
    ua += 0x7FFFu + ((ua >> 16) & 1u);
    ub += 0x7FFFu + ((ub >> 16) & 1u);
    return __builtin_amdgcn_perm(ub, ua, 0x07060302);
}
// Packed bf16 convert: HW v_cvt_pk_bf16_f32 on gfx950 (1 op) else rne2.
static __device__ __forceinline__ uint pk2(float a, float b) {
#if __has_builtin(__builtin_amdgcn_cvt_pk_bf16_f32)
    auto r = __builtin_amdgcn_cvt_pk_bf16_f32(a, b);
    return __builtin_bit_cast(uint, r);
#else
    return rne2(a, b);
#endif
}

// exp2 -> packed bf16x2 of (a,b)
static __device__ __forceinline__ uint e2pk(float a, float b) {
    return pk2(__builtin_amdgcn_exp2f(a), __builtin_amdgcn_exp2f(b));
}

// Redistribute packed exp pairs (t0lo..t1hi) from S^T layout to PV B-frag
// layout: 2x permlane32_swap + 2x permlane16_swap (element-wise verified).
static __device__ __forceinline__ bf16x8 redist(uint t0lo, uint t0hi,
                                                uint t1lo, uint t1hi,
                                                int lane) {
#if __has_builtin(__builtin_amdgcn_permlane32_swap) && __has_builtin(__builtin_amdgcn_permlane16_swap)
    auto rl = __builtin_amdgcn_permlane32_swap(t0lo, t1lo, false, false);
    auto rh = __builtin_amdgcn_permlane32_swap(t0hi, t1hi, false, false);
    auto sl = __builtin_amdgcn_permlane16_swap(rl[0], rl[1], false, false);
    auto sh = __builtin_amdgcn_permlane16_swap(rh[0], rh[1], false, false);
    uint4 pw = {sl[0], sh[0], sl[1], sh[1]};
#else
    uint a0 = __shfl_xor((int)t0lo, 32), b0 = __shfl_xor((int)t1lo, 32);
    uint a1 = __shfl_xor((int)t0hi, 32), b1 = __shfl_xor((int)t1hi, 32);
    uint Xl = (lane & 32) ? b0 : t0lo,  Yl = (lane & 32) ? t1lo : a0;
    uint Xh = (lane & 32) ? b1 : t0hi,  Yh = (lane & 32) ? t1hi : a1;
    uint sXl = __shfl_xor((int)Xl, 16), sYl = __shfl_xor((int)Yl, 16);
    uint sXh = __shfl_xor((int)Xh, 16), sYh = __shfl_xor((int)Yh, 16);
    uint4 pw = {(lane & 16) ? sYl : Xl, (lane & 16) ? sYh : Xh,
                (lane & 16) ? Yl : sXl, (lane & 16) ? Yh : sXh};
#endif
    return __builtin_bit_cast(bf16x8, pw);
}

#define LSQ 72       // qkv/out LDS row stride (64 + 8 pad), ushorts

// ---------------------------------------------------------------------------
// Kernel 0: weight transposes + x fp32->bf16 conversion, ONE dispatch. (r8)
// ---------------------------------------------------------------------------
__global__ __launch_bounds__(256) void wcvt_all(
    const float* __restrict__ wq, const float* __restrict__ wo,
    const float* __restrict__ x,
    ushort* __restrict__ wqT, ushort* __restrict__ woT,
    ushort* __restrict__ xbf)
{
    const int t  = threadIdx.x;
    const int bx = blockIdx.x;
    if (bx >= 32) {
        const size_t base = ((size_t)(bx - 32) * 8 + blockIdx.y) * 4096 + t * 16;
        float4 f0 = *(const float4*)(x + base);
        float4 f1 = *(const float4*)(x + base + 4);
        float4 f2 = *(const float4*)(x + base + 8);
        float4 f3 = *(const float4*)(x + base + 12);
        uint4 w0, w1;
        w0.x = pk2(f0.x, f0.y); w0.y = pk2(f0.z, f0.w);
        w0.z = pk2(f1.x, f1.y); w0.w = pk2(f1.z, f1.w);
        w1.x = pk2(f2.x, f2.y); w1.y = pk2(f2.z, f2.w);
        w1.z = pk2(f3.x, f3.y); w1.w = pk2(f3.z, f3.w);
        *(uint4*)&xbf[base]     = w0;
        *(uint4*)&xbf[base + 8] = w1;
        return;
    }
    __shared__ float T[32][33];
    const float* w; ushort* wT; int N, n0;
    if (bx < 24) { w = wq; wT = wqT; N = 768; n0 = bx * 32; }
    else         { w = wo; wT = woT; N = 256; n0 = (bx - 24) * 32; }
    const int k0 = blockIdx.y * 32;
    {
        int tr = t >> 3, tc = (t & 7) * 4;
        *(float4*)&T[tr][tc] = *(const float4*)(w + (size_t)(k0 + tr) * N + n0 + tc);
    }
    __syncthreads();
    int nl = t >> 3, kq = (t & 7) * 4;
    ushort4 pk;
    pk.x = f2bf(T[kq + 0][nl]); pk.y = f2bf(T[kq + 1][nl]);
    pk.z = f2bf(T[kq + 2][nl]); pk.w = f2bf(T[kq + 3][nl]);
    *(ushort4*)&wT[(size_t)(n0 + nl) * 256 + k0 + kq] = pk;
}

// ---------------------------------------------------------------------------
// Kernel 1: QKV projection, bf16 MFMA, scalar reg-prefetch. (r8, proven)
// ---------------------------------------------------------------------------
__global__ __launch_bounds__(256, 3) void qkv_gemm(
    const ushort* __restrict__ xb_, const ushort* __restrict__ wT,
    const float* __restrict__ bias,
    ushort* __restrict__ qo, ushort* __restrict__ ko, ushort* __restrict__ vo)
{
    __shared__ ushort As[64 * LSQ];
    __shared__ ushort Bs[128 * LSQ];
    const int tid  = threadIdx.x;
    const int wid  = tid >> 6;
    const int lane = tid & 63;
    const int lq   = lane & 15;
    const int quad = lane >> 4;
    const int wm   = wid & 1;
    const int wn   = wid >> 1;
    const int m0   = blockIdx.y * 64;
    const int n0   = blockIdx.x * 128;
    const bool isV = (blockIdx.x >= 4);

    const int ar0 = tid >> 3,         ac0 = (tid & 7) * 8;
    const int ar1 = (tid + 256) >> 3;
    const int br0 = tid >> 3,         bc0 = (tid & 7) * 8;
    const int br1 = (tid + 256) >> 3;
    const int br2 = (tid + 512) >> 3;
    const int br3 = (tid + 768) >> 3;

    const ushort* xb = xb_ + (size_t)m0 * 256;
    const ushort* wb = wT  + (size_t)n0 * 256;

    f32x4 acc[8];
#pragma unroll
    for (int i = 0; i < 8; ++i) acc[i] = {0.f, 0.f, 0.f, 0.f};

    uint4 ra0 = *(const uint4*)(xb + (size_t)ar0 * 256 + ac0);
    uint4 ra1 = *(const uint4*)(xb + (size_t)ar1 * 256 + ac0);
    uint4 rb0 = *(const uint4*)(wb + (size_t)br0 * 256 + bc0);
    uint4 rb1 = *(const uint4*)(wb + (size_t)br1 * 256 + bc0);
    uint4 rb2 = *(const uint4*)(wb + (size_t)br2 * 256 + bc0);
    uint4 rb3 = *(const uint4*)(wb + (size_t)br3 * 256 + bc0);

    for (int k0 = 0; k0 < 256; k0 += 64) {
        __syncthreads();
        *(uint4*)&As[ar0 * LSQ + ac0] = ra0;
        *(uint4*)&As[ar1 * LSQ + ac0] = ra1;
        *(uint4*)&Bs[br0 * LSQ + bc0] = rb0;
        *(uint4*)&Bs[br1 * LSQ + bc0] = rb1;
        *(uint4*)&Bs[br2 * LSQ + bc0] = rb2;
        *(uint4*)&Bs[br3 * LSQ + bc0] = rb3;
        __syncthreads();

        const int kn = (k0 + 64) & 255;
        ra0 = *(const uint4*)(xb + (size_t)ar0 * 256 + kn + ac0);
        ra1 = *(const uint4*)(xb + (size_t)ar1 * 256 + kn + ac0);
        rb0 = *(const uint4*)(wb + (size_t)br0 * 256 + kn + bc0);
        rb1 = *(const uint4*)(wb + (size_t)br1 * 256 + kn + bc0);
        rb2 = *(const uint4*)(wb + (size_t)br2 * 256 + kn + bc0);
        rb3 = *(const uint4*)(wb + (size_t)br3 * 256 + kn + bc0);

#pragma unroll
        for (int kh = 0; kh < 2; ++kh) {
            bf16x8 af[2], bfg[4];
#pragma unroll
            for (int mi = 0; mi < 2; ++mi)
                af[mi]  = *(const bf16x8*)&As[(wm * 32 + mi * 16 + lq) * LSQ + kh * 32 + quad * 8];
#pragma unroll
            for (int ni = 0; ni < 4; ++ni)
                bfg[ni] = *(const bf16x8*)&Bs[(wn * 64 + ni * 16 + lq) * LSQ + kh * 32 + quad * 8];
            if (isV) {
#pragma unroll
                for (int mi = 0; mi < 2; ++mi)
#pragma unroll
                    for (int ni = 0; ni < 4; ++ni)
                        acc[mi * 4 + ni] = __builtin_amdgcn_mfma_f32_16x16x32_bf16(
                            af[mi], bfg[ni], acc[mi * 4 + ni], 0, 0, 0);
            } else {
#pragma unroll
                for (int ni = 0; ni < 4; ++ni)
#pragma unroll
                    for (int mi = 0; mi < 2; ++mi)
                        acc[ni * 2 + mi] = __builtin_amdgcn_mfma_f32_16x16x32_bf16(
                            bfg[ni], af[mi], acc[ni * 2 + mi], 0, 0, 0);
            }
        }
    }

    if (!isV) {
#pragma unroll
        for (int ni = 0; ni < 4; ++ni) {
            int nb = n0 + wn * 64 + ni * 16 + quad * 4;
            float4 bs = *(const float4*)(bias + nb);
            int h   = (nb >> 5) & 7;
            int dh0 = nb & 31;
            bool  isQ = (nb < 256);
            float sc  = isQ ? QSCALE : 1.0f;
            ushort* dst = isQ ? qo : ko;
#pragma unroll
            for (int mi = 0; mi < 2; ++mi) {
                int m   = m0 + wm * 32 + mi * 16 + lq;
                int b   = m >> 11, seq = m & 2047;
                f32x4 c = acc[ni * 2 + mi];
                ushort4 pk;
                pk.x = f2bf((c[0] + bs.x) * sc); pk.y = f2bf((c[1] + bs.y) * sc);
                pk.z = f2bf((c[2] + bs.z) * sc); pk.w = f2bf((c[3] + bs.w) * sc);
                *(ushort4*)&dst[(((size_t)b * NH + h) * SEQ + seq) * DH + dh0] = pk;
            }
        }
    } else {
#pragma unroll
        for (int ni = 0; ni < 4; ++ni) {
            int n  = n0 + wn * 64 + ni * 16 + lq;
            int h  = (n >> 5) & 7;
            int dh = n & 31;
            float bsc = bias[n];
#pragma unroll
            for (int mi = 0; mi < 2; ++mi) {
                int mb  = m0 + wm * 32 + mi * 16 + quad * 4;
                int b   = mb >> 11, seq = mb & 2047;
                f32x4 c = acc[mi * 4 + ni];
                ushort4 pk;
                pk.x = f2bf(c[0] + bsc); pk.y = f2bf(c[1] + bsc);
                pk.z = f2bf(c[2] + bsc); pk.w = f2bf(c[3] + bsc);
                *(ushort4*)&vo[(((size_t)b * NH + h) * DH + dh) * SEQ + seq] = pk;
            }
        }
    }
}

// ---------------------------------------------------------------------------
// Kernel 2: MFMA flash attention v8.  v7 + explicit 1-deep reg prefetch.
// Post-mortem r6: v7 (LDS-free, direct L2 loads) hit 57us, worse than v6's
// ~40us.  L2 residency worked (FETCH 6.2MB, conflicts ~0) but VGPR_Count=44
// shows the compiler did NOT hoist loads across iterations: each of 16
// iterations serialized {4 L2 loads (~200-300cy) -> QK -> exp2 -> redist ->
// PV} with only ~3 waves/SIMD to overlap.  Fix: explicit software pipeline -
// consume this iter's fragments from named regs, then immediately issue
// next iter's 4 loads (same pattern as qkv_gemm's proven reg-prefetch).
// +16 VGPR (44 -> ~64), well under LB(256,5)'s 102 cap.
// ---------------------------------------------------------------------------
__global__ __launch_bounds__(256, 5) void attn_mfma(
    const ushort* __restrict__ qb, const ushort* __restrict__ kb,
    const ushort* __restrict__ vtb, ushort* __restrict__ a_bf)
{
    __shared__ float Red[3][64][20];   // waves 1-3: O(16) + l0,l1

    const int tid  = threadIdx.x;
    const int wid  = tid >> 6;          // kv quarter 0..3
    const int lane = tid & 63;
    const int lq   = lane & 15;
    const int quad = lane >> 4;

    // XCD-aware bijective swizzle: 2048 blocks = 8 XCDs x 256; each XCD gets
    // 4 whole (b,h) K/V streams (1MB) resident in its L2.
    const int lin = blockIdx.x + (blockIdx.y << 6) + (blockIdx.z << 9);
    const int swz = ((lin & 7) << 8) | (lin >> 3);
    const int qc  = swz & 63;
    const int h   = (swz >> 6) & 7;
    const int b   = swz >> 9;
    const int bh  = b * NH + h;
    const int q0  = qc * 32;

    const ushort* qbase = qb + ((size_t)bh * SEQ + q0) * DH;
    const bf16x8 qf0 = *(const bf16x8*)(qbase + (size_t)lq * DH + quad * 8);
    const bf16x8 qf1 = *(const bf16x8*)(qbase + (size_t)(16 + lq) * DH + quad * 8);

    // per-lane bases into this wave's KV quarter
    const ushort* kp = kb  + ((size_t)bh * SEQ + wid * 512 + lq) * DH + quad * 8;
    const ushort* vp = vtb + ((size_t)bh * DH + lq) * SEQ + wid * 512 + quad * 8;

    f32x4 o0 = {0.f,0.f,0.f,0.f}, o1 = {0.f,0.f,0.f,0.f};
    f32x4 o2 = {0.f,0.f,0.f,0.f}, o3 = {0.f,0.f,0.f,0.f};
    f32x4 la0 = {0.f,0.f,0.f,0.f}, la1 = {0.f,0.f,0.f,0.f};
    const bf16x8 ones = {0x3F80, 0x3F80, 0x3F80, 0x3F80,
                         0x3F80, 0x3F80, 0x3F80, 0x3F80};  // bf16(1.0) x8

    // prime the pipeline: iteration 0's fragments
    uint4 fk0 = *(const uint4*)(kp);
    uint4 fk1 = *(const uint4*)(kp + 16 * DH);
    uint4 fv0 = *(const uint4*)(vp);
    uint4 fv1 = *(const uint4*)(vp + 16 * SEQ);

#pragma unroll 4
    for (int kt = 0; kt < 512; kt += 32) {
        bf16x8 kf0 = __builtin_bit_cast(bf16x8, fk0);
        bf16x8 kf1 = __builtin_bit_cast(bf16x8, fk1);
        bf16x8 v0  = __builtin_bit_cast(bf16x8, fv0);
        bf16x8 v1  = __builtin_bit_cast(bf16x8, fv1);

        // issue next iteration's loads NOW (wraps on last iter; unused)
        const int kn = (kt + 32) & 511;
        fk0 = *(const uint4*)(kp + (size_t)kn * DH);
        fk1 = *(const uint4*)(kp + (size_t)(kn + 16) * DH);
        fv0 = *(const uint4*)(vp + kn);
        fv1 = *(const uint4*)(vp + 16 * SEQ + kn);

        f32x4 z = {0.f, 0.f, 0.f, 0.f};
        f32x4 sa0 = __builtin_amdgcn_mfma_f32_16x16x32_bf16(kf0, qf0, z, 0, 0, 0);
        f32x4 sa1 = __builtin_amdgcn_mfma_f32_16x16x32_bf16(kf1, qf0, z, 0, 0, 0);
        f32x4 sb0 = __builtin_amdgcn_mfma_f32_16x16x32_bf16(kf0, qf1, z, 0, 0, 0);
        f32x4 sb1 = __builtin_amdgcn_mfma_f32_16x16x32_bf16(kf1, qf1, z, 0, 0, 0);

        bf16x8 p0 = redist(e2pk(sa0[0], sa0[1]), e2pk(sa0[2], sa0[3]),
                           e2pk(sa1[0], sa1[1]), e2pk(sa1[2], sa1[3]), lane);
        bf16x8 p1 = redist(e2pk(sb0[0], sb0[1]), e2pk(sb0[2], sb0[3]),
                           e2pk(sb1[0], sb1[1]), e2pk(sb1[2], sb1[3]), lane);

        o0  = __builtin_amdgcn_mfma_f32_16x16x32_bf16(v0,   p0, o0,  0, 0, 0);
        o1  = __builtin_amdgcn_mfma_f32_16x16x32_bf16(v1,   p0, o1,  0, 0, 0);
        o2  = __builtin_amdgcn_mfma_f32_16x16x32_bf16(v0,   p1, o2,  0, 0, 0);
        o3  = __builtin_amdgcn_mfma_f32_16x16x32_bf16(v1,   p1, o3,  0, 0, 0);
        la0 = __builtin_amdgcn_mfma_f32_16x16x32_bf16(ones, p0, la0, 0, 0, 0);
        la1 = __builtin_amdgcn_mfma_f32_16x16x32_bf16(ones, p1, la1, 0, 0, 0);
    }

    // ---- combine quarters: O and l are plain sums (no-max softmax) ----
    if (wid) {
        float* r = &Red[wid - 1][lane][0];
        *(f32x4*)&r[0]  = o0;  *(f32x4*)&r[4]  = o1;
        *(f32x4*)&r[8]  = o2;  *(f32x4*)&r[12] = o3;
        r[16] = la0[0]; r[17] = la1[0];
    }
    __syncthreads();
    if (wid == 0) {
        float l0 = la0[0], l1 = la1[0];
#pragma unroll
        for (int j = 0; j < 3; ++j) {
            const float* r = &Red[j][lane][0];
            f32x4 a0 = *(const f32x4*)&r[0],  a1 = *(const f32x4*)&r[4];
            f32x4 a2 = *(const f32x4*)&r[8],  a3 = *(const f32x4*)&r[12];
            o0 += a0; o1 += a1; o2 += a2; o3 += a3;
            l0 += r[16]; l1 += r[17];
        }
        float inv0 = 1.0f / l0;
        float inv1 = 1.0f / l1;

        ushort* dst0 = a_bf + ((size_t)b * SEQ + q0 + lq) * DMODEL + h * DH;
        ushort* dst1 = dst0 + 16 * DMODEL;
        uint2 w0, w1;
        w0.x = pk2(o0[0] * inv0, o0[1] * inv0);
        w0.y = pk2(o0[2] * inv0, o0[3] * inv0);
        w1.x = pk2(o1[0] * inv0, o1[1] * inv0);
        w1.y = pk2(o1[2] * inv0, o1[3] * inv0);
        *(uint2*)&dst0[quad * 4]      = w0;
        *(uint2*)&dst0[16 + quad * 4] = w1;
        w0.x = pk2(o2[0] * inv1, o2[1] * inv1);
        w0.y = pk2(o2[2] * inv1, o2[3] * inv1);
        w1.x = pk2(o3[0] * inv1, o3[1] * inv1);
        w1.y = pk2(o3[2] * inv1, o3[3] * inv1);
        *(uint2*)&dst1[quad * 4]      = w0;
        *(uint2*)&dst1[16 + quad * 4] = w1;
    }
}

// ---------------------------------------------------------------------------
// Kernel 3: out projection, bf16 MFMA, scalar reg-prefetch. (r8, proven)
// ---------------------------------------------------------------------------
__global__ __launch_bounds__(256) void out_gemm(
    const ushort* __restrict__ a, const ushort* __restrict__ wT,
    const float* __restrict__ bias, float* __restrict__ out)
{
    __shared__ ushort As[64 * LSQ];
    __shared__ ushort Bs[64 * LSQ];
    const int tid  = threadIdx.x;
    const int wid  = tid >> 6;
    const int lane = tid & 63;
    const int lq   = lane & 15;
    const int quad = lane >> 4;
    const int wm   = wid & 1;
    const int wn   = wid >> 1;
    const int m0   = blockIdx.y * 64;
    const int n0   = blockIdx.x * 64;

    const int f0 = tid, f1 = tid + 256;
    const int r0 = f0 >> 3, c0 = (f0 & 7) * 8;
    const int r1 = f1 >> 3, c1 = (f1 & 7) * 8;

    const ushort* ab = a  + (size_t)m0 * 256;
    const ushort* wb = wT + (size_t)n0 * 256;

    f32x4 acc[4];
#pragma unroll
    for (int i = 0; i < 4; ++i) acc[i] = {0.f, 0.f, 0.f, 0.f};

    uint4 ra0 = *(const uint4*)(ab + (size_t)r0 * 256 + c0);
    uint4 ra1 = *(const uint4*)(ab + (size_t)r1 * 256 + c1);
    uint4 rb0 = *(const uint4*)(wb + (size_t)r0 * 256 + c0);
    uint4 rb1 = *(const uint4*)(wb + (size_t)r1 * 256 + c1);

    for (int k0 = 0; k0 < 256; k0 += 64) {
        __syncthreads();
        *(uint4*)&As[r0 * LSQ + c0] = ra0;
        *(uint4*)&As[r1 * LSQ + c1] = ra1;
        *(uint4*)&Bs[r0 * LSQ + c0] = rb0;
        *(uint4*)&Bs[r1 * LSQ + c1] = rb1;
        __syncthreads();

        const int kn = (k0 + 64) & 255;
        ra0 = *(const uint4*)(ab + (size_t)r0 * 256 + kn + c0);
        ra1 = *(const uint4*)(ab + (size_t)r1 * 256 + kn + c1);
        rb0 = *(const uint4*)(wb + (size_t)r0 * 256 + kn + c0);
        rb1 = *(const uint4*)(wb + (size_t)r1 * 256 + kn + c1);

#pragma unroll
        for (int kh = 0; kh < 2; ++kh) {
            bf16x8 af[2], bfg[2];
#pragma unroll
            for (int mi = 0; mi < 2; ++mi)
                af[mi]  = *(const bf16x8*)&As[(wm * 32 + mi * 16 + lq) * LSQ + kh * 32 + quad * 8];
#pragma unroll
            for (int ni = 0; ni < 2; ++ni)
                bfg[ni] = *(const bf16x8*)&Bs[(wn * 32 + ni * 16 + lq) * LSQ + kh * 32 + quad * 8];
#pragma unroll
            for (int ni = 0; ni < 2; ++ni)
#pragma unroll
                for (int mi = 0; mi < 2; ++mi)
                    acc[ni * 2 + mi] = __builtin_amdgcn_mfma_f32_16x16x32_bf16(
                        bfg[ni], af[mi], acc[ni * 2 + mi], 0, 0, 0);
        }
    }

#pragma unroll
    for (int ni = 0; ni < 2; ++ni) {
        int nb = n0 + wn * 32 + ni * 16 + quad * 4;
        float4 bs = *(const float4*)(bias + nb);
#pragma unroll
        for (int mi = 0; mi < 2; ++mi) {
            int m = m0 + wm * 32 + mi * 16 + lq;
            f32x4 c = acc[ni * 2 + mi];
            float4 o;
            o.x = c[0] + bs.x; o.y = c[1] + bs.y;
            o.z = c[2] + bs.z; o.w = c[3] + bs.w;
            *(float4*)&out[(size_t)m * DMODEL + nb] = o;
        }
    }
}

extern "C" void kernel_launch(void* const* d_in, const int* in_sizes, int n_in,
                              void* d_out, int out_size, void* d_ws, size_t ws_size,
                              hipStream_t stream) {
    const float* x     = (const float*)d_in[0];
    const float* w_qkv = (const float*)d_in[1];
    const float* b_qkv = (const float*)d_in[2];
    const float* w_out = (const float*)d_in[3];
    const float* b_out = (const float*)d_in[4];
    float* out = (float*)d_out;

    const size_t TSZ = (size_t)MTOT * DMODEL;
    ushort* q_ws = (ushort*)d_ws;          // Q pre-scaled bf16 [b,h,s,dh]
    ushort* k_ws = q_ws + TSZ;             // K bf16 [b,h,s,dh]
    ushort* v_ws = k_ws + TSZ;             // V^T bf16 [b,h,dh,s]
    ushort* a_bf = v_ws + TSZ;             // attn out bf16 [b,s,d]
    ushort* xbf  = a_bf + TSZ;             // x bf16
    ushort* wqT  = xbf + TSZ;
    ushort* woT  = wqT + 768 * 256;

    wcvt_all<<<dim3(96, 8), 256, 0, stream>>>(w_qkv, w_out, x, wqT, woT, xbf);
    qkv_gemm<<<dim3(6, 128), 256, 0, stream>>>(xbf, wqT, b_qkv, q_ws, k_ws, v_ws);
    attn_mfma<<<dim3(64, NH, BATCH), 256, 0, stream>>>(
        q_ws, k_ws, v_ws, a_bf);
    out_gemm<<<dim3(4, 128), 256, 0, stream>>>(a_bf, woT, b_out, out);
}

// Round 9
// 122.141 us; speedup vs baseline: 1.0989x; 1.0989x over previous
//
#include <hip/hip_runtime.h>
#include <hip/hip_bf16.h>
#include <math.h>

#define BATCH  4
#define SEQ    2048
#define DMODEL 256
#define NH     8
#define DH     32
#define MTOT   (BATCH*SEQ)   // 8192
// Q is pre-scaled by 256^-0.5 * log2(e) so attention uses p = exp2(q.k) raw.
#define QSCALE 0.09016844005556021f

typedef short  bf16x8 __attribute__((ext_vector_type(8)));
typedef float  f32x4  __attribute__((ext_vector_type(4)));

static __device__ __forceinline__ ushort f2bf(float f) {
    __hip_bfloat16 h = __float2bfloat16(f);
    return __builtin_bit_cast(ushort, h);
}
// RNE-pack two fp32 -> packed bf16x2 (low = a, high = b), software fallback.
static __device__ __forceinline__ uint rne2(float a, float b) {
    uint ua = __builtin_bit_cast(uint, a);
    uint ub = __builtin_bit_cast(uint, b);
    ua += 0x7FFFu + ((ua >> 16) & 1u);
    ub += 0x7FFFu + ((ub >> 16) & 1u);
    return __builtin_amdgcn_perm(ub, ua, 0x07060302);
}
// Packed bf16 convert: HW v_cvt_pk_bf16_f32 on gfx950 (1 op) else rne2.
static __device__ __forceinline__ uint pk2(float a, float b) {
#if __has_builtin(__builtin_amdgcn_cvt_pk_bf16_f32)
    auto r = __builtin_amdgcn_cvt_pk_bf16_f32(a, b);
    return __builtin_bit_cast(uint, r);
#else
    return rne2(a, b);
#endif
}

// exp2 -> packed bf16x2 of (a,b)
static __device__ __forceinline__ uint e2pk(float a, float b) {
    return pk2(__builtin_amdgcn_exp2f(a), __builtin_amdgcn_exp2f(b));
}

// Redistribute packed exp pairs (t0lo..t1hi) from S^T layout to PV B-frag
// layout: 2x permlane32_swap + 2x permlane16_swap (element-wise verified).
static __device__ __forceinline__ bf16x8 redist(uint t0lo, uint t0hi,
                                                uint t1lo, uint t1hi,
                                                int lane) {
#if __has_builtin(__builtin_amdgcn_permlane32_swap) && __has_builtin(__builtin_amdgcn_permlane16_swap)
    auto rl = __builtin_amdgcn_permlane32_swap(t0lo, t1lo, false, false);
    auto rh = __builtin_amdgcn_permlane32_swap(t0hi, t1hi, false, false);
    auto sl = __builtin_amdgcn_permlane16_swap(rl[0], rl[1], false, false);
    auto sh = __builtin_amdgcn_permlane16_swap(rh[0], rh[1], false, false);
    uint4 pw = {sl[0], sh[0], sl[1], sh[1]};
#else
    uint a0 = __shfl_xor((int)t0lo, 32), b0 = __shfl_xor((int)t1lo, 32);
    uint a1 = __shfl_xor((int)t0hi, 32), b1 = __shfl_xor((int)t1hi, 32);
    uint Xl = (lane & 32) ? b0 : t0lo,  Yl = (lane & 32) ? t1lo : a0;
    uint Xh = (lane & 32) ? b1 : t0hi,  Yh = (lane & 32) ? t1hi : a1;
    uint sXl = __shfl_xor((int)Xl, 16), sYl = __shfl_xor((int)Yl, 16);
    uint sXh = __shfl_xor((int)Xh, 16), sYh = __shfl_xor((int)Yh, 16);
    uint4 pw = {(lane & 16) ? sYl : Xl, (lane & 16) ? sYh : Xh,
                (lane & 16) ? Yl : sXl, (lane & 16) ? Yh : sXh};
#endif
    return __builtin_bit_cast(bf16x8, pw);
}

#define LSQ 72       // qkv/out LDS row stride (64 + 8 pad), ushorts

// ---------------------------------------------------------------------------
// Kernel 0: weight transposes + x fp32->bf16 conversion, ONE dispatch. (r8)
// ---------------------------------------------------------------------------
__global__ __launch_bounds__(256) void wcvt_all(
    const float* __restrict__ wq, const float* __restrict__ wo,
    const float* __restrict__ x,
    ushort* __restrict__ wqT, ushort* __restrict__ woT,
    ushort* __restrict__ xbf)
{
    const int t  = threadIdx.x;
    const int bx = blockIdx.x;
    if (bx >= 32) {
        const size_t base = ((size_t)(bx - 32) * 8 + blockIdx.y) * 4096 + t * 16;
        float4 f0 = *(const float4*)(x + base);
        float4 f1 = *(const float4*)(x + base + 4);
        float4 f2 = *(const float4*)(x + base + 8);
        float4 f3 = *(const float4*)(x + base + 12);
        uint4 w0, w1;
        w0.x = pk2(f0.x, f0.y); w0.y = pk2(f0.z, f0.w);
        w0.z = pk2(f1.x, f1.y); w0.w = pk2(f1.z, f1.w);
        w1.x = pk2(f2.x, f2.y); w1.y = pk2(f2.z, f2.w);
        w1.z = pk2(f3.x, f3.y); w1.w = pk2(f3.z, f3.w);
        *(uint4*)&xbf[base]     = w0;
        *(uint4*)&xbf[base + 8] = w1;
        return;
    }
    __shared__ float T[32][33];
    const float* w; ushort* wT; int N, n0;
    if (bx < 24) { w = wq; wT = wqT; N = 768; n0 = bx * 32; }
    else         { w = wo; wT = woT; N = 256; n0 = (bx - 24) * 32; }
    const int k0 = blockIdx.y * 32;
    {
        int tr = t >> 3, tc = (t & 7) * 4;
        *(float4*)&T[tr][tc] = *(const float4*)(w + (size_t)(k0 + tr) * N + n0 + tc);
    }
    __syncthreads();
    int nl = t >> 3, kq = (t & 7) * 4;
    ushort4 pk;
    pk.x = f2bf(T[kq + 0][nl]); pk.y = f2bf(T[kq + 1][nl]);
    pk.z = f2bf(T[kq + 2][nl]); pk.w = f2bf(T[kq + 3][nl]);
    *(ushort4*)&wT[(size_t)(n0 + nl) * 256 + k0 + kq] = pk;
}

// ---------------------------------------------------------------------------
// Kernel 1: QKV projection, bf16 MFMA, scalar reg-prefetch. (r8, proven)
// ---------------------------------------------------------------------------
__global__ __launch_bounds__(256, 3) void qkv_gemm(
    const ushort* __restrict__ xb_, const ushort* __restrict__ wT,
    const float* __restrict__ bias,
    ushort* __restrict__ qo, ushort* __restrict__ ko, ushort* __restrict__ vo)
{
    __shared__ ushort As[64 * LSQ];
    __shared__ ushort Bs[128 * LSQ];
    const int tid  = threadIdx.x;
    const int wid  = tid >> 6;
    const int lane = tid & 63;
    const int lq   = lane & 15;
    const int quad = lane >> 4;
    const int wm   = wid & 1;
    const int wn   = wid >> 1;
    const int m0   = blockIdx.y * 64;
    const int n0   = blockIdx.x * 128;
    const bool isV = (blockIdx.x >= 4);

    const int ar0 = tid >> 3,         ac0 = (tid & 7) * 8;
    const int ar1 = (tid + 256) >> 3;
    const int br0 = tid >> 3,         bc0 = (tid & 7) * 8;
    const int br1 = (tid + 256) >> 3;
    const int br2 = (tid + 512) >> 3;
    const int br3 = (tid + 768) >> 3;

    const ushort* xb = xb_ + (size_t)m0 * 256;
    const ushort* wb = wT  + (size_t)n0 * 256;

    f32x4 acc[8];
#pragma unroll
    for (int i = 0; i < 8; ++i) acc[i] = {0.f, 0.f, 0.f, 0.f};

    uint4 ra0 = *(const uint4*)(xb + (size_t)ar0 * 256 + ac0);
    uint4 ra1 = *(const uint4*)(xb + (size_t)ar1 * 256 + ac0);
    uint4 rb0 = *(const uint4*)(wb + (size_t)br0 * 256 + bc0);
    uint4 rb1 = *(const uint4*)(wb + (size_t)br1 * 256 + bc0);
    uint4 rb2 = *(const uint4*)(wb + (size_t)br2 * 256 + bc0);
    uint4 rb3 = *(const uint4*)(wb + (size_t)br3 * 256 + bc0);

    for (int k0 = 0; k0 < 256; k0 += 64) {
        __syncthreads();
        *(uint4*)&As[ar0 * LSQ + ac0] = ra0;
        *(uint4*)&As[ar1 * LSQ + ac0] = ra1;
        *(uint4*)&Bs[br0 * LSQ + bc0] = rb0;
        *(uint4*)&Bs[br1 * LSQ + bc0] = rb1;
        *(uint4*)&Bs[br2 * LSQ + bc0] = rb2;
        *(uint4*)&Bs[br3 * LSQ + bc0] = rb3;
        __syncthreads();

        const int kn = (k0 + 64) & 255;
        ra0 = *(const uint4*)(xb + (size_t)ar0 * 256 + kn + ac0);
        ra1 = *(const uint4*)(xb + (size_t)ar1 * 256 + kn + ac0);
        rb0 = *(const uint4*)(wb + (size_t)br0 * 256 + kn + bc0);
        rb1 = *(const uint4*)(wb + (size_t)br1 * 256 + kn + bc0);
        rb2 = *(const uint4*)(wb + (size_t)br2 * 256 + kn + bc0);
        rb3 = *(const uint4*)(wb + (size_t)br3 * 256 + kn + bc0);

#pragma unroll
        for (int kh = 0; kh < 2; ++kh) {
            bf16x8 af[2], bfg[4];
#pragma unroll
            for (int mi = 0; mi < 2; ++mi)
                af[mi]  = *(const bf16x8*)&As[(wm * 32 + mi * 16 + lq) * LSQ + kh * 32 + quad * 8];
#pragma unroll
            for (int ni = 0; ni < 4; ++ni)
                bfg[ni] = *(const bf16x8*)&Bs[(wn * 64 + ni * 16 + lq) * LSQ + kh * 32 + quad * 8];
            if (isV) {
#pragma unroll
                for (int mi = 0; mi < 2; ++mi)
#pragma unroll
                    for (int ni = 0; ni < 4; ++ni)
                        acc[mi * 4 + ni] = __builtin_amdgcn_mfma_f32_16x16x32_bf16(
                            af[mi], bfg[ni], acc[mi * 4 + ni], 0, 0, 0);
            } else {
#pragma unroll
                for (int ni = 0; ni < 4; ++ni)
#pragma unroll
                    for (int mi = 0; mi < 2; ++mi)
                        acc[ni * 2 + mi] = __builtin_amdgcn_mfma_f32_16x16x32_bf16(
                            bfg[ni], af[mi], acc[ni * 2 + mi], 0, 0, 0);
            }
        }
    }

    if (!isV) {
#pragma unroll
        for (int ni = 0; ni < 4; ++ni) {
            int nb = n0 + wn * 64 + ni * 16 + quad * 4;
            float4 bs = *(const float4*)(bias + nb);
            int h   = (nb >> 5) & 7;
            int dh0 = nb & 31;
            bool  isQ = (nb < 256);
            float sc  = isQ ? QSCALE : 1.0f;
            ushort* dst = isQ ? qo : ko;
#pragma unroll
            for (int mi = 0; mi < 2; ++mi) {
                int m   = m0 + wm * 32 + mi * 16 + lq;
                int b   = m >> 11, seq = m & 2047;
                f32x4 c = acc[ni * 2 + mi];
                ushort4 pk;
                pk.x = f2bf((c[0] + bs.x) * sc); pk.y = f2bf((c[1] + bs.y) * sc);
                pk.z = f2bf((c[2] + bs.z) * sc); pk.w = f2bf((c[3] + bs.w) * sc);
                *(ushort4*)&dst[(((size_t)b * NH + h) * SEQ + seq) * DH + dh0] = pk;
            }
        }
    } else {
#pragma unroll
        for (int ni = 0; ni < 4; ++ni) {
            int n  = n0 + wn * 64 + ni * 16 + lq;
            int h  = (n >> 5) & 7;
            int dh = n & 31;
            float bsc = bias[n];
#pragma unroll
            for (int mi = 0; mi < 2; ++mi) {
                int mb  = m0 + wm * 32 + mi * 16 + quad * 4;
                int b   = mb >> 11, seq = mb & 2047;
                f32x4 c = acc[mi * 4 + ni];
                ushort4 pk;
                pk.x = f2bf(c[0] + bsc); pk.y = f2bf(c[1] + bsc);
                pk.z = f2bf(c[2] + bsc); pk.w = f2bf(c[3] + bsc);
                *(ushort4*)&vo[(((size_t)b * NH + h) * DH + dh) * SEQ + seq] = pk;
            }
        }
    }
}

// ---------------------------------------------------------------------------
// Kernel 2: MFMA flash attention v9.  Back to v6's staged structure (best
// measured, ~40us) with its occupancy limiter removed.
// Post-mortem r6/r8: LDS-free direct-L2 (v7/v8) = 57.6us regardless of reg
// prefetch -> falsified.  v6's LDS staging wins (cooperative tile loads,
// 131MB vs 512MB L2 traffic).  v6 was capped at 2 blocks/CU (58KB LDS incl.
// 20.5KB epilogue-only Red buffer; grid 512).
// v9: (a) Red ALIASED onto staging LDS (disjoint in time) -> 38.9KB;
// (b) 4-way KV split, KVBLK=64: 8 waves = 2 q-chunks x 4 quarters over
// 64 q-rows; grid 1024; 4 blocks/CU now fit -> up to 8 waves/SIMD (2x v6)
// at v6's measured 64 VGPR.  Per-wave inner math identical to v6.
// ---------------------------------------------------------------------------
__global__ __launch_bounds__(512, 4) void attn_mfma(
    const ushort* __restrict__ qb, const ushort* __restrict__ kb,
    const ushort* __restrict__ vtb, ushort* __restrict__ a_bf)
{
    // K: 4 quarters x [64][40] ushorts = 10240; V^T: 4 x [32][72] = 9216.
    // Red (epilogue only) aliases the front: 2*3*64*20 floats = 30720B.
    __shared__ ushort SM[19456];   // 38,912 B

    const int tid  = threadIdx.x;
    const int wid  = tid >> 6;
    const int lane = tid & 63;
    const int lq   = lane & 15;
    const int quad = lane >> 4;
    const int qc   = wid & 1;       // q-chunk within block (2 x 32 rows)
    const int quarter = wid >> 1;   // KV quarter 0..3

    // XCD swizzle: 1024 blocks = 8 XCDs x 128; each XCD gets 4 complete
    // (b,h) K/V streams (1MB, L2-fit).
    const int lin = blockIdx.x + (blockIdx.y << 5) + (blockIdx.z << 8);
    const int swz = ((lin & 7) << 7) | (lin >> 3);
    const int qpair = swz & 31;
    const int h   = (swz >> 5) & 7;
    const int b   = swz >> 8;
    const int bh  = b * NH + h;
    const int q0  = qpair * 64 + qc * 32;

    const ushort* qbase = qb + ((size_t)bh * SEQ + q0) * DH;
    const bf16x8 qf0 = *(const bf16x8*)(qbase + (size_t)lq * DH + quad * 8);
    const bf16x8 qf1 = *(const bf16x8*)(qbase + (size_t)(16 + lq) * DH + quad * 8);

    const ushort* kbase  = kb  + (size_t)bh * SEQ * DH;
    const ushort* vtbase = vtb + (size_t)bh * DH * SEQ;

    // Staging maps: 1024 K-vectors (4q x 64r x 4cv) + 1024 V-vectors
    // (4q x 32r x 8cv); thread f handles vector f and f+512 of each.
    const int kv0 = tid, kv1 = tid + 512;
    const int kq0 = kv0 >> 8, kr0 = (kv0 & 255) >> 2, kc0 = (kv0 & 3) * 8;
    const int kq1 = kv1 >> 8, kr1 = (kv1 & 255) >> 2, kc1 = (kv1 & 3) * 8;
    const int gk0 = (kq0 * 512 + kr0) * DH + kc0;
    const int gk1 = (kq1 * 512 + kr1) * DH + kc1;
    const int lk0 = kq0 * 2560 + kr0 * 40 + kc0;
    const int lk1 = kq1 * 2560 + kr1 * 40 + kc1;
    const int vq0 = kv0 >> 8, vr0 = (kv0 & 255) >> 3, vc0 = (kv0 & 7) * 8;
    const int vq1 = kv1 >> 8, vr1 = (kv1 & 255) >> 3, vc1 = (kv1 & 7) * 8;
    const int gv0 = vr0 * SEQ + vq0 * 512 + vc0;
    const int gv1 = vr1 * SEQ + vq1 * 512 + vc1;
    const int lv0 = 10240 + vq0 * 2304 + vr0 * 72 + vc0;
    const int lv1 = 10240 + vq1 * 2304 + vr1 * 72 + vc1;

    uint4 fka = *(const uint4*)(kbase + gk0);
    uint4 fkb = *(const uint4*)(kbase + gk1);
    uint4 fva = *(const uint4*)(vtbase + gv0);
    uint4 fvb = *(const uint4*)(vtbase + gv1);

    const ushort* Kq = SM + quarter * 2560;
    const ushort* Vq = SM + 10240 + quarter * 2304;

    f32x4 o0 = {0.f,0.f,0.f,0.f}, o1 = {0.f,0.f,0.f,0.f};
    f32x4 o2 = {0.f,0.f,0.f,0.f}, o3 = {0.f,0.f,0.f,0.f};
    f32x4 la0 = {0.f,0.f,0.f,0.f}, la1 = {0.f,0.f,0.f,0.f};
    const bf16x8 ones = {0x3F80, 0x3F80, 0x3F80, 0x3F80,
                         0x3F80, 0x3F80, 0x3F80, 0x3F80};  // bf16(1.0) x8

    for (int t = 0; t < 8; ++t) {
        __syncthreads();
        *(uint4*)&SM[lk0] = fka;
        *(uint4*)&SM[lk1] = fkb;
        *(uint4*)&SM[lv0] = fva;
        *(uint4*)&SM[lv1] = fvb;
        __syncthreads();

        {   // prefetch next tile (wraps on last iter; values unused)
            const int tn = (t + 1) & 7;
            fka = *(const uint4*)(kbase + (size_t)tn * 64 * DH + gk0);
            fkb = *(const uint4*)(kbase + (size_t)tn * 64 * DH + gk1);
            fva = *(const uint4*)(vtbase + tn * 64 + gv0);
            fvb = *(const uint4*)(vtbase + tn * 64 + gv1);
        }

#pragma unroll
        for (int s = 0; s < 2; ++s) {
            bf16x8 kf0 = *(const bf16x8*)&Kq[(s * 32 + lq) * 40 + quad * 8];
            bf16x8 kf1 = *(const bf16x8*)&Kq[(s * 32 + 16 + lq) * 40 + quad * 8];
            f32x4 z = {0.f, 0.f, 0.f, 0.f};
            f32x4 sa0 = __builtin_amdgcn_mfma_f32_16x16x32_bf16(kf0, qf0, z, 0, 0, 0);
            f32x4 sa1 = __builtin_amdgcn_mfma_f32_16x16x32_bf16(kf1, qf0, z, 0, 0, 0);
            f32x4 sb0 = __builtin_amdgcn_mfma_f32_16x16x32_bf16(kf0, qf1, z, 0, 0, 0);
            f32x4 sb1 = __builtin_amdgcn_mfma_f32_16x16x32_bf16(kf1, qf1, z, 0, 0, 0);

            bf16x8 v0 = *(const bf16x8*)&Vq[lq        * 72 + s * 32 + quad * 8];
            bf16x8 v1 = *(const bf16x8*)&Vq[(16 + lq) * 72 + s * 32 + quad * 8];

            bf16x8 p0 = redist(e2pk(sa0[0], sa0[1]), e2pk(sa0[2], sa0[3]),
                               e2pk(sa1[0], sa1[1]), e2pk(sa1[2], sa1[3]), lane);
            bf16x8 p1 = redist(e2pk(sb0[0], sb0[1]), e2pk(sb0[2], sb0[3]),
                               e2pk(sb1[0], sb1[1]), e2pk(sb1[2], sb1[3]), lane);

            o0  = __builtin_amdgcn_mfma_f32_16x16x32_bf16(v0,   p0, o0,  0, 0, 0);
            o1  = __builtin_amdgcn_mfma_f32_16x16x32_bf16(v1,   p0, o1,  0, 0, 0);
            o2  = __builtin_amdgcn_mfma_f32_16x16x32_bf16(v0,   p1, o2,  0, 0, 0);
            o3  = __builtin_amdgcn_mfma_f32_16x16x32_bf16(v1,   p1, o3,  0, 0, 0);
            la0 = __builtin_amdgcn_mfma_f32_16x16x32_bf16(ones, p0, la0, 0, 0, 0);
            la1 = __builtin_amdgcn_mfma_f32_16x16x32_bf16(ones, p1, la1, 0, 0, 0);
        }
    }

    // ---- combine quarters (pure sums, no-max softmax). Red aliases SM. ----
    __syncthreads();                       // last compute read done
    float* Red = (float*)SM;
    if (quarter) {
        float* r = &Red[(((qc * 3) + quarter - 1) * 64 + lane) * 20];
        *(f32x4*)&r[0]  = o0;  *(f32x4*)&r[4]  = o1;
        *(f32x4*)&r[8]  = o2;  *(f32x4*)&r[12] = o3;
        r[16] = la0[0]; r[17] = la1[0];
    }
    __syncthreads();
    if (quarter == 0) {
        float l0 = la0[0], l1 = la1[0];
#pragma unroll
        for (int j = 0; j < 3; ++j) {
            const float* r = &Red[(((qc * 3) + j) * 64 + lane) * 20];
            f32x4 a0 = *(const f32x4*)&r[0],  a1 = *(const f32x4*)&r[4];
            f32x4 a2 = *(const f32x4*)&r[8],  a3 = *(const f32x4*)&r[12];
            o0 += a0; o1 += a1; o2 += a2; o3 += a3;
            l0 += r[16]; l1 += r[17];
        }
        float inv0 = 1.0f / l0;
        float inv1 = 1.0f / l1;

        ushort* dst0 = a_bf + ((size_t)b * SEQ + q0 + lq) * DMODEL + h * DH;
        ushort* dst1 = dst0 + 16 * DMODEL;
        uint2 w0, w1;
        w0.x = pk2(o0[0] * inv0, o0[1] * inv0);
        w0.y = pk2(o0[2] * inv0, o0[3] * inv0);
        w1.x = pk2(o1[0] * inv0, o1[1] * inv0);
        w1.y = pk2(o1[2] * inv0, o1[3] * inv0);
        *(uint2*)&dst0[quad * 4]      = w0;
        *(uint2*)&dst0[16 + quad * 4] = w1;
        w0.x = pk2(o2[0] * inv1, o2[1] * inv1);
        w0.y = pk2(o2[2] * inv1, o2[3] * inv1);
        w1.x = pk2(o3[0] * inv1, o3[1] * inv1);
        w1.y = pk2(o3[2] * inv1, o3[3] * inv1);
        *(uint2*)&dst1[quad * 4]      = w0;
        *(uint2*)&dst1[16 + quad * 4] = w1;
    }
}

// ---------------------------------------------------------------------------
// Kernel 3: out projection, bf16 MFMA, scalar reg-prefetch. (r8, proven)
// ---------------------------------------------------------------------------
__global__ __launch_bounds__(256) void out_gemm(
    const ushort* __restrict__ a, const ushort* __restrict__ wT,
    const float* __restrict__ bias, float* __restrict__ out)
{
    __shared__ ushort As[64 * LSQ];
    __shared__ ushort Bs[64 * LSQ];
    const int tid  = threadIdx.x;
    const int wid  = tid >> 6;
    const int lane = tid & 63;
    const int lq   = lane & 15;
    const int quad = lane >> 4;
    const int wm   = wid & 1;
    const int wn   = wid >> 1;
    const int m0   = blockIdx.y * 64;
    const int n0   = blockIdx.x * 64;

    const int f0 = tid, f1 = tid + 256;
    const int r0 = f0 >> 3, c0 = (f0 & 7) * 8;
    const int r1 = f1 >> 3, c1 = (f1 & 7) * 8;

    const ushort* ab = a  + (size_t)m0 * 256;
    const ushort* wb = wT + (size_t)n0 * 256;

    f32x4 acc[4];
#pragma unroll
    for (int i = 0; i < 4; ++i) acc[i] = {0.f, 0.f, 0.f, 0.f};

    uint4 ra0 = *(const uint4*)(ab + (size_t)r0 * 256 + c0);
    uint4 ra1 = *(const uint4*)(ab + (size_t)r1 * 256 + c1);
    uint4 rb0 = *(const uint4*)(wb + (size_t)r0 * 256 + c0);
    uint4 rb1 = *(const uint4*)(wb + (size_t)r1 * 256 + c1);

    for (int k0 = 0; k0 < 256; k0 += 64) {
        __syncthreads();
        *(uint4*)&As[r0 * LSQ + c0] = ra0;
        *(uint4*)&As[r1 * LSQ + c1] = ra1;
        *(uint4*)&Bs[r0 * LSQ + c0] = rb0;
        *(uint4*)&Bs[r1 * LSQ + c1] = rb1;
        __syncthreads();

        const int kn = (k0 + 64) & 255;
        ra0 = *(const uint4*)(ab + (size_t)r0 * 256 + kn + c0);
        ra1 = *(const uint4*)(ab + (size_t)r1 * 256 + kn + c1);
        rb0 = *(const uint4*)(wb + (size_t)r0 * 256 + kn + c0);
        rb1 = *(const uint4*)(wb + (size_t)r1 * 256 + kn + c1);

#pragma unroll
        for (int kh = 0; kh < 2; ++kh) {
            bf16x8 af[2], bfg[2];
#pragma unroll
            for (int mi = 0; mi < 2; ++mi)
                af[mi]  = *(const bf16x8*)&As[(wm * 32 + mi * 16 + lq) * LSQ + kh * 32 + quad * 8];
#pragma unroll
            for (int ni = 0; ni < 2; ++ni)
                bfg[ni] = *(const bf16x8*)&Bs[(wn * 32 + ni * 16 + lq) * LSQ + kh * 32 + quad * 8];
#pragma unroll
            for (int ni = 0; ni < 2; ++ni)
#pragma unroll
                for (int mi = 0; mi < 2; ++mi)
                    acc[ni * 2 + mi] = __builtin_amdgcn_mfma_f32_16x16x32_bf16(
                        bfg[ni], af[mi], acc[ni * 2 + mi], 0, 0, 0);
        }
    }

#pragma unroll
    for (int ni = 0; ni < 2; ++ni) {
        int nb = n0 + wn * 32 + ni * 16 + quad * 4;
        float4 bs = *(const float4*)(bias + nb);
#pragma unroll
        for (int mi = 0; mi < 2; ++mi) {
            int m = m0 + wm * 32 + mi * 16 + lq;
            f32x4 c = acc[ni * 2 + mi];
            float4 o;
            o.x = c[0] + bs.x; o.y = c[1] + bs.y;
            o.z = c[2] + bs.z; o.w = c[3] + bs.w;
            *(float4*)&out[(size_t)m * DMODEL + nb] = o;
        }
    }
}

extern "C" void kernel_launch(void* const* d_in, const int* in_sizes, int n_in,
                              void* d_out, int out_size, void* d_ws, size_t ws_size,
                              hipStream_t stream) {
    const float* x     = (const float*)d_in[0];
    const float* w_qkv = (const float*)d_in[1];
    const float* b_qkv = (const float*)d_in[2];
    const float* w_out = (const float*)d_in[3];
    const float* b_out = (const float*)d_in[4];
    float* out = (float*)d_out;

    const size_t TSZ = (size_t)MTOT * DMODEL;
    ushort* q_ws = (ushort*)d_ws;          // Q pre-scaled bf16 [b,h,s,dh]
    ushort* k_ws = q_ws + TSZ;             // K bf16 [b,h,s,dh]
    ushort* v_ws = k_ws + TSZ;             // V^T bf16 [b,h,dh,s]
    ushort* a_bf = v_ws + TSZ;             // attn out bf16 [b,s,d]
    ushort* xbf  = a_bf + TSZ;             // x bf16
    ushort* wqT  = xbf + TSZ;
    ushort* woT  = wqT + 768 * 256;

    wcvt_all<<<dim3(96, 8), 256, 0, stream>>>(w_qkv, w_out, x, wqT, woT, xbf);
    qkv_gemm<<<dim3(6, 128), 256, 0, stream>>>(xbf, wqT, b_qkv, q_ws, k_ws, v_ws);
    attn_mfma<<<dim3(32, NH, BATCH), 512, 0, stream>>>(
        q_ws, k_ws, v_ws, a_bf);
    out_gemm<<<dim3(4, 128), 256, 0, stream>>>(a_bf, woT, b_out, out);
}

// Round 10
// 120.117 us; speedup vs baseline: 1.1174x; 1.0168x over previous
//
#include <hip/hip_runtime.h>
#include <hip/hip_bf16.h>
#include <math.h>

#define BATCH  4
#define SEQ    2048
#define DMODEL 256
#define NH     8
#define DH     32
#define MTOT   (BATCH*SEQ)   // 8192
// Q is pre-scaled by 256^-0.5 * log2(e) so attention uses p = exp2(q.k) raw.
#define QSCALE 0.09016844005556021f

typedef short  bf16x8 __attribute__((ext_vector_type(8)));
typedef float  f32x4  __attribute__((ext_vector_type(4)));

static __device__ __forceinline__ ushort f2bf(float f) {
    __hip_bfloat16 h = __float2bfloat16(f);
    return __builtin_bit_cast(ushort, h);
}
// RNE-pack two fp32 -> packed bf16x2 (low = a, high = b), software fallback.
static __device__ __forceinline__ uint rne2(float a, float b) {
    uint ua = __builtin_bit_cast(uint, a);
    uint ub = __builtin_bit_cast(uint, b);
    ua += 0x7FFFu + ((ua >> 16) & 1u);
    ub += 0x7FFFu + ((ub >> 16) & 1u);
    return __builtin_amdgcn_perm(ub, ua, 0x07060302);
}
// Packed bf16 convert: HW v_cvt_pk_bf16_f32 on gfx950 (1 op) else rne2.
static __device__ __forceinline__ uint pk2(float a, float b) {
#if __has_builtin(__builtin_amdgcn_cvt_pk_bf16_f32)
    auto r = __builtin_amdgcn_cvt_pk_bf16_f32(a, b);
    return __builtin_bit_cast(uint, r);
#else
    return rne2(a, b);
#endif
}

// exp2 -> packed bf16x2 of (a,b)
static __device__ __forceinline__ uint e2pk(float a, float b) {
    return pk2(__builtin_amdgcn_exp2f(a), __builtin_amdgcn_exp2f(b));
}

// Redistribute packed exp pairs (t0lo..t1hi) from S^T layout to PV B-frag
// layout: 2x permlane32_swap + 2x permlane16_swap (element-wise verified).
static __device__ __forceinline__ bf16x8 redist(uint t0lo, uint t0hi,
                                                uint t1lo, uint t1hi,
                                                int lane) {
#if __has_builtin(__builtin_amdgcn_permlane32_swap) && __has_builtin(__builtin_amdgcn_permlane16_swap)
    auto rl = __builtin_amdgcn_permlane32_swap(t0lo, t1lo, false, false);
    auto rh = __builtin_amdgcn_permlane32_swap(t0hi, t1hi, false, false);
    auto sl = __builtin_amdgcn_permlane16_swap(rl[0], rl[1], false, false);
    auto sh = __builtin_amdgcn_permlane16_swap(rh[0], rh[1], false, false);
    uint4 pw = {sl[0], sh[0], sl[1], sh[1]};
#else
    uint a0 = __shfl_xor((int)t0lo, 32), b0 = __shfl_xor((int)t1lo, 32);
    uint a1 = __shfl_xor((int)t0hi, 32), b1 = __shfl_xor((int)t1hi, 32);
    uint Xl = (lane & 32) ? b0 : t0lo,  Yl = (lane & 32) ? t1lo : a0;
    uint Xh = (lane & 32) ? b1 : t0hi,  Yh = (lane & 32) ? t1hi : a1;
    uint sXl = __shfl_xor((int)Xl, 16), sYl = __shfl_xor((int)Yl, 16);
    uint sXh = __shfl_xor((int)Xh, 16), sYh = __shfl_xor((int)Yh, 16);
    uint4 pw = {(lane & 16) ? sYl : Xl, (lane & 16) ? sYh : Xh,
                (lane & 16) ? Yl : sXl, (lane & 16) ? Yh : sXh};
#endif
    return __builtin_bit_cast(bf16x8, pw);
}

#define LSQ 72       // qkv/out LDS row stride (64 + 8 pad), ushorts
#define KS_STRIDE 40
#define VT_STRIDE 136

// ---------------------------------------------------------------------------
// Kernel 0: weight transposes ONLY (x-conversion fused into qkv_gemm, r10).
// 32x8 grid (was 96x8): blocks 0..23 transpose w_qkv, 24..31 w_out.
// ---------------------------------------------------------------------------
__global__ __launch_bounds__(256) void wcvt_all(
    const float* __restrict__ wq, const float* __restrict__ wo,
    ushort* __restrict__ wqT, ushort* __restrict__ woT)
{
    const int t  = threadIdx.x;
    const int bx = blockIdx.x;
    __shared__ float T[32][33];
    const float* w; ushort* wT; int N, n0;
    if (bx < 24) { w = wq; wT = wqT; N = 768; n0 = bx * 32; }
    else         { w = wo; wT = woT; N = 256; n0 = (bx - 24) * 32; }
    const int k0 = blockIdx.y * 32;
    {
        int tr = t >> 3, tc = (t & 7) * 4;
        *(float4*)&T[tr][tc] = *(const float4*)(w + (size_t)(k0 + tr) * N + n0 + tc);
    }
    __syncthreads();
    int nl = t >> 3, kq = (t & 7) * 4;
    ushort4 pk;
    pk.x = f2bf(T[kq + 0][nl]); pk.y = f2bf(T[kq + 1][nl]);
    pk.z = f2bf(T[kq + 2][nl]); pk.w = f2bf(T[kq + 3][nl]);
    *(ushort4*)&wT[(size_t)(n0 + nl) * 256 + k0 + kq] = pk;
}

// ---------------------------------------------------------------------------
// Kernel 1: QKV projection, bf16 MFMA, scalar reg-prefetch.  (r10: reads x
// directly as f32, converting to bf16 in-register during A-staging — drops
// the xbf round-trip and the 512-block x-branch of wcvt.)
// ---------------------------------------------------------------------------
__global__ __launch_bounds__(256, 3) void qkv_gemm(
    const float* __restrict__ x_, const ushort* __restrict__ wT,
    const float* __restrict__ bias,
    ushort* __restrict__ qo, ushort* __restrict__ ko, ushort* __restrict__ vo)
{
    __shared__ ushort As[64 * LSQ];
    __shared__ ushort Bs[128 * LSQ];
    const int tid  = threadIdx.x;
    const int wid  = tid >> 6;
    const int lane = tid & 63;
    const int lq   = lane & 15;
    const int quad = lane >> 4;
    const int wm   = wid & 1;
    const int wn   = wid >> 1;
    const int m0   = blockIdx.y * 64;
    const int n0   = blockIdx.x * 128;
    const bool isV = (blockIdx.x >= 4);

    const int ar0 = tid >> 3,         ac0 = (tid & 7) * 8;
    const int ar1 = (tid + 256) >> 3;
    const int br0 = tid >> 3,         bc0 = (tid & 7) * 8;
    const int br1 = (tid + 256) >> 3;
    const int br2 = (tid + 512) >> 3;
    const int br3 = (tid + 768) >> 3;

    const float*  xb = x_ + (size_t)m0 * 256;
    const ushort* wb = wT + (size_t)n0 * 256;

    f32x4 acc[8];
#pragma unroll
    for (int i = 0; i < 8; ++i) acc[i] = {0.f, 0.f, 0.f, 0.f};

    float4 fa0a = *(const float4*)(xb + (size_t)ar0 * 256 + ac0);
    float4 fa0b = *(const float4*)(xb + (size_t)ar0 * 256 + ac0 + 4);
    float4 fa1a = *(const float4*)(xb + (size_t)ar1 * 256 + ac0);
    float4 fa1b = *(const float4*)(xb + (size_t)ar1 * 256 + ac0 + 4);
    uint4 rb0 = *(const uint4*)(wb + (size_t)br0 * 256 + bc0);
    uint4 rb1 = *(const uint4*)(wb + (size_t)br1 * 256 + bc0);
    uint4 rb2 = *(const uint4*)(wb + (size_t)br2 * 256 + bc0);
    uint4 rb3 = *(const uint4*)(wb + (size_t)br3 * 256 + bc0);

    for (int k0 = 0; k0 < 256; k0 += 64) {
        __syncthreads();
        {
            uint4 wa;
            wa.x = pk2(fa0a.x, fa0a.y); wa.y = pk2(fa0a.z, fa0a.w);
            wa.z = pk2(fa0b.x, fa0b.y); wa.w = pk2(fa0b.z, fa0b.w);
            *(uint4*)&As[ar0 * LSQ + ac0] = wa;
            wa.x = pk2(fa1a.x, fa1a.y); wa.y = pk2(fa1a.z, fa1a.w);
            wa.z = pk2(fa1b.x, fa1b.y); wa.w = pk2(fa1b.z, fa1b.w);
            *(uint4*)&As[ar1 * LSQ + ac0] = wa;
        }
        *(uint4*)&Bs[br0 * LSQ + bc0] = rb0;
        *(uint4*)&Bs[br1 * LSQ + bc0] = rb1;
        *(uint4*)&Bs[br2 * LSQ + bc0] = rb2;
        *(uint4*)&Bs[br3 * LSQ + bc0] = rb3;
        __syncthreads();

        const int kn = (k0 + 64) & 255;
        fa0a = *(const float4*)(xb + (size_t)ar0 * 256 + kn + ac0);
        fa0b = *(const float4*)(xb + (size_t)ar0 * 256 + kn + ac0 + 4);
        fa1a = *(const float4*)(xb + (size_t)ar1 * 256 + kn + ac0);
        fa1b = *(const float4*)(xb + (size_t)ar1 * 256 + kn + ac0 + 4);
        rb0 = *(const uint4*)(wb + (size_t)br0 * 256 + kn + bc0);
        rb1 = *(const uint4*)(wb + (size_t)br1 * 256 + kn + bc0);
        rb2 = *(const uint4*)(wb + (size_t)br2 * 256 + kn + bc0);
        rb3 = *(const uint4*)(wb + (size_t)br3 * 256 + kn + bc0);

#pragma unroll
        for (int kh = 0; kh < 2; ++kh) {
            bf16x8 af[2], bfg[4];
#pragma unroll
            for (int mi = 0; mi < 2; ++mi)
                af[mi]  = *(const bf16x8*)&As[(wm * 32 + mi * 16 + lq) * LSQ + kh * 32 + quad * 8];
#pragma unroll
            for (int ni = 0; ni < 4; ++ni)
                bfg[ni] = *(const bf16x8*)&Bs[(wn * 64 + ni * 16 + lq) * LSQ + kh * 32 + quad * 8];
            if (isV) {
#pragma unroll
                for (int mi = 0; mi < 2; ++mi)
#pragma unroll
                    for (int ni = 0; ni < 4; ++ni)
                        acc[mi * 4 + ni] = __builtin_amdgcn_mfma_f32_16x16x32_bf16(
                            af[mi], bfg[ni], acc[mi * 4 + ni], 0, 0, 0);
            } else {
#pragma unroll
                for (int ni = 0; ni < 4; ++ni)
#pragma unroll
                    for (int mi = 0; mi < 2; ++mi)
                        acc[ni * 2 + mi] = __builtin_amdgcn_mfma_f32_16x16x32_bf16(
                            bfg[ni], af[mi], acc[ni * 2 + mi], 0, 0, 0);
            }
        }
    }

    if (!isV) {
#pragma unroll
        for (int ni = 0; ni < 4; ++ni) {
            int nb = n0 + wn * 64 + ni * 16 + quad * 4;
            float4 bs = *(const float4*)(bias + nb);
            int h   = (nb >> 5) & 7;
            int dh0 = nb & 31;
            bool  isQ = (nb < 256);
            float sc  = isQ ? QSCALE : 1.0f;
            ushort* dst = isQ ? qo : ko;
#pragma unroll
            for (int mi = 0; mi < 2; ++mi) {
                int m   = m0 + wm * 32 + mi * 16 + lq;
                int b   = m >> 11, seq = m & 2047;
                f32x4 c = acc[ni * 2 + mi];
                ushort4 pk;
                pk.x = f2bf((c[0] + bs.x) * sc); pk.y = f2bf((c[1] + bs.y) * sc);
                pk.z = f2bf((c[2] + bs.z) * sc); pk.w = f2bf((c[3] + bs.w) * sc);
                *(ushort4*)&dst[(((size_t)b * NH + h) * SEQ + seq) * DH + dh0] = pk;
            }
        }
    } else {
#pragma unroll
        for (int ni = 0; ni < 4; ++ni) {
            int n  = n0 + wn * 64 + ni * 16 + lq;
            int h  = (n >> 5) & 7;
            int dh = n & 31;
            float bsc = bias[n];
#pragma unroll
            for (int mi = 0; mi < 2; ++mi) {
                int mb  = m0 + wm * 32 + mi * 16 + quad * 4;
                int b   = mb >> 11, seq = mb & 2047;
                f32x4 c = acc[mi * 4 + ni];
                ushort4 pk;
                pk.x = f2bf(c[0] + bsc); pk.y = f2bf(c[1] + bsc);
                pk.z = f2bf(c[2] + bsc); pk.w = f2bf(c[3] + bsc);
                *(ushort4*)&vo[(((size_t)b * NH + h) * DH + dh) * SEQ + seq] = pk;
            }
        }
    }
}

// ---------------------------------------------------------------------------
// Kernel 2: MFMA flash attention v6 (EXACT r3 code — best measured total,
// 116.5us).  2-way KV-split, s-block-fused, 512 threads, grid (16,NH,BATCH).
// v7/v8 (LDS-free) and v9 (4-way split, aliased Red) all measured equal or
// worse; reverting to the proven structure.
// ---------------------------------------------------------------------------
__global__ __launch_bounds__(512, 4) void attn_mfma(
    const ushort* __restrict__ qb, const ushort* __restrict__ kb,
    const ushort* __restrict__ vtb, ushort* __restrict__ a_bf)
{
    __shared__ ushort KsA[128 * KS_STRIDE];
    __shared__ ushort KsB[128 * KS_STRIDE];
    __shared__ ushort VsA[32 * VT_STRIDE];
    __shared__ ushort VsB[32 * VT_STRIDE];
    __shared__ float  Red[4][64][20];   // partner wave's O(16) + l0,l1

    const int tid  = threadIdx.x;
    const int wid  = tid >> 6;
    const int lane = tid & 63;
    const int lq   = lane & 15;
    const int quad = lane >> 4;
    const int half = wid >> 2;          // 0: even tiles, 1: odd tiles
    const int wq   = wid & 3;           // q-chunk within block

    // XCD-aware bijective swizzle: 512 blocks = 8 XCDs x 64; contiguous
    // work ids (sharing (b,h) K/V) land on one XCD's L2.
    const int lin = blockIdx.x + (blockIdx.y << 4) + (blockIdx.z << 7);
    const int swz = ((lin & 7) << 6) | (lin >> 3);
    const int h   = (swz >> 4) & 7;
    const int b   = swz >> 7;
    const int bh  = b * NH + h;
    const int q0  = (swz & 15) * 128 + wq * 32;

    const ushort* qbase = qb + ((size_t)bh * SEQ + q0) * DH;
    const bf16x8 qf0 = *(const bf16x8*)(qbase + (size_t)lq * DH + quad * 8);
    const bf16x8 qf1 = *(const bf16x8*)(qbase + (size_t)(16 + lq) * DH + quad * 8);

    const ushort* kbase  = kb  + (size_t)bh * SEQ * DH;
    const ushort* vtbase = vtb + (size_t)bh * DH * SEQ;

    const int kgo = (tid >> 2) * DH + (tid & 3) * 8;
    const int klo = (tid >> 2) * KS_STRIDE + (tid & 3) * 8;
    const int vgo = (tid >> 4) * SEQ + (tid & 15) * 8;
    const int vlo = (tid >> 4) * VT_STRIDE + (tid & 15) * 8;

    uint4 krA = *(const uint4*)(kbase  + kgo);
    uint4 vrA = *(const uint4*)(vtbase + vgo);
    uint4 krB = *(const uint4*)(kbase  + 128 * DH + kgo);
    uint4 vrB = *(const uint4*)(vtbase + 128 + vgo);

    const ushort* Ksw = half ? KsB : KsA;
    const ushort* Vsw = half ? VsB : VsA;

    f32x4 o0 = {0.f,0.f,0.f,0.f}, o1 = {0.f,0.f,0.f,0.f};
    f32x4 o2 = {0.f,0.f,0.f,0.f}, o3 = {0.f,0.f,0.f,0.f};
    f32x4 la0 = {0.f,0.f,0.f,0.f}, la1 = {0.f,0.f,0.f,0.f};
    const bf16x8 ones = {0x3F80, 0x3F80, 0x3F80, 0x3F80,
                         0x3F80, 0x3F80, 0x3F80, 0x3F80};  // bf16(1.0) x8

    for (int kt = 0; kt < SEQ; kt += 256) {
        __syncthreads();
        *(uint4*)&KsA[klo] = krA;
        *(uint4*)&VsA[vlo] = vrA;
        *(uint4*)&KsB[klo] = krB;
        *(uint4*)&VsB[vlo] = vrB;
        __syncthreads();

        {   // unconditional prefetch (wraps on last iter; values unused)
            const int ka  = (kt + 256) & (SEQ - 1);
            const int kbn = (kt + 384) & (SEQ - 1);
            krA = *(const uint4*)(kbase  + (size_t)ka  * DH + kgo);
            vrA = *(const uint4*)(vtbase + ka  + vgo);
            krB = *(const uint4*)(kbase  + (size_t)kbn * DH + kgo);
            vrB = *(const uint4*)(vtbase + kbn + vgo);
        }

        // ---- per s-block: QK^T (4 MFMA) -> exp2/pack/permlane -> PV ----
#pragma unroll
        for (int s = 0; s < 4; ++s) {
            bf16x8 kf0 = *(const bf16x8*)&Ksw[((2*s    ) * 16 + lq) * KS_STRIDE + quad * 8];
            bf16x8 kf1 = *(const bf16x8*)&Ksw[((2*s + 1) * 16 + lq) * KS_STRIDE + quad * 8];
            f32x4 z = {0.f, 0.f, 0.f, 0.f};
            f32x4 sa0 = __builtin_amdgcn_mfma_f32_16x16x32_bf16(kf0, qf0, z, 0, 0, 0);
            f32x4 sa1 = __builtin_amdgcn_mfma_f32_16x16x32_bf16(kf1, qf0, z, 0, 0, 0);
            f32x4 sb0 = __builtin_amdgcn_mfma_f32_16x16x32_bf16(kf0, qf1, z, 0, 0, 0);
            f32x4 sb1 = __builtin_amdgcn_mfma_f32_16x16x32_bf16(kf1, qf1, z, 0, 0, 0);

            bf16x8 v0 = *(const bf16x8*)&Vsw[lq        * VT_STRIDE + s * 32 + quad * 8];
            bf16x8 v1 = *(const bf16x8*)&Vsw[(16 + lq) * VT_STRIDE + s * 32 + quad * 8];

            bf16x8 p0 = redist(e2pk(sa0[0], sa0[1]), e2pk(sa0[2], sa0[3]),
                               e2pk(sa1[0], sa1[1]), e2pk(sa1[2], sa1[3]), lane);
            bf16x8 p1 = redist(e2pk(sb0[0], sb0[1]), e2pk(sb0[2], sb0[3]),
                               e2pk(sb1[0], sb1[1]), e2pk(sb1[2], sb1[3]), lane);

            o0  = __builtin_amdgcn_mfma_f32_16x16x32_bf16(v0,   p0, o0,  0, 0, 0);
            o1  = __builtin_amdgcn_mfma_f32_16x16x32_bf16(v1,   p0, o1,  0, 0, 0);
            o2  = __builtin_amdgcn_mfma_f32_16x16x32_bf16(v0,   p1, o2,  0, 0, 0);
            o3  = __builtin_amdgcn_mfma_f32_16x16x32_bf16(v1,   p1, o3,  0, 0, 0);
            la0 = __builtin_amdgcn_mfma_f32_16x16x32_bf16(ones, p0, la0, 0, 0, 0);
            la1 = __builtin_amdgcn_mfma_f32_16x16x32_bf16(ones, p1, la1, 0, 0, 0);
        }
    }

    // ---- combine halves: O and l are plain sums (no-max softmax) ----
    __syncthreads();
    if (half) {
        float* r = &Red[wq][lane][0];
        r[0]  = o0[0]; r[1]  = o0[1]; r[2]  = o0[2]; r[3]  = o0[3];
        r[4]  = o1[0]; r[5]  = o1[1]; r[6]  = o1[2]; r[7]  = o1[3];
        r[8]  = o2[0]; r[9]  = o2[1]; r[10] = o2[2]; r[11] = o2[3];
        r[12] = o3[0]; r[13] = o3[1]; r[14] = o3[2]; r[15] = o3[3];
        r[16] = la0[0]; r[17] = la1[0];
    }
    __syncthreads();
    if (!half) {
        const float* r = &Red[wq][lane][0];
        o0[0] += r[0];  o0[1] += r[1];  o0[2] += r[2];  o0[3] += r[3];
        o1[0] += r[4];  o1[1] += r[5];  o1[2] += r[6];  o1[3] += r[7];
        o2[0] += r[8];  o2[1] += r[9];  o2[2] += r[10]; o2[3] += r[11];
        o3[0] += r[12]; o3[1] += r[13]; o3[2] += r[14]; o3[3] += r[15];
        float inv0 = 1.0f / (la0[0] + r[16]);
        float inv1 = 1.0f / (la1[0] + r[17]);

        ushort* dst0 = a_bf + ((size_t)b * SEQ + q0 + lq) * DMODEL + h * DH;
        ushort* dst1 = dst0 + 16 * DMODEL;
        uint2 w0, w1;
        w0.x = pk2(o0[0] * inv0, o0[1] * inv0);
        w0.y = pk2(o0[2] * inv0, o0[3] * inv0);
        w1.x = pk2(o1[0] * inv0, o1[1] * inv0);
        w1.y = pk2(o1[2] * inv0, o1[3] * inv0);
        *(uint2*)&dst0[quad * 4]      = w0;
        *(uint2*)&dst0[16 + quad * 4] = w1;
        w0.x = pk2(o2[0] * inv1, o2[1] * inv1);
        w0.y = pk2(o2[2] * inv1, o2[3] * inv1);
        w1.x = pk2(o3[0] * inv1, o3[1] * inv1);
        w1.y = pk2(o3[2] * inv1, o3[3] * inv1);
        *(uint2*)&dst1[quad * 4]      = w0;
        *(uint2*)&dst1[16 + quad * 4] = w1;
    }
}

// ---------------------------------------------------------------------------
// Kernel 3: out projection, bf16 MFMA, scalar reg-prefetch. (r8, proven)
// ---------------------------------------------------------------------------
__global__ __launch_bounds__(256) void out_gemm(
    const ushort* __restrict__ a, const ushort* __restrict__ wT,
    const float* __restrict__ bias, float* __restrict__ out)
{
    __shared__ ushort As[64 * LSQ];
    __shared__ ushort Bs[64 * LSQ];
    const int tid  = threadIdx.x;
    const int wid  = tid >> 6;
    const int lane = tid & 63;
    const int lq   = lane & 15;
    const int quad = lane >> 4;
    const int wm   = wid & 1;
    const int wn   = wid >> 1;
    const int m0   = blockIdx.y * 64;
    const int n0   = blockIdx.x * 64;

    const int f0 = tid, f1 = tid + 256;
    const int r0 = f0 >> 3, c0 = (f0 & 7) * 8;
    const int r1 = f1 >> 3, c1 = (f1 & 7) * 8;

    const ushort* ab = a  + (size_t)m0 * 256;
    const ushort* wb = wT + (size_t)n0 * 256;

    f32x4 acc[4];
#pragma unroll
    for (int i = 0; i < 4; ++i) acc[i] = {0.f, 0.f, 0.f, 0.f};

    uint4 ra0 = *(const uint4*)(ab + (size_t)r0 * 256 + c0);
    uint4 ra1 = *(const uint4*)(ab + (size_t)r1 * 256 + c1);
    uint4 rb0 = *(const uint4*)(wb + (size_t)r0 * 256 + c0);
    uint4 rb1 = *(const uint4*)(wb + (size_t)r1 * 256 + c1);

    for (int k0 = 0; k0 < 256; k0 += 64) {
        __syncthreads();
        *(uint4*)&As[r0 * LSQ + c0] = ra0;
        *(uint4*)&As[r1 * LSQ + c1] = ra1;
        *(uint4*)&Bs[r0 * LSQ + c0] = rb0;
        *(uint4*)&Bs[r1 * LSQ + c1] = rb1;
        __syncthreads();

        const int kn = (k0 + 64) & 255;
        ra0 = *(const uint4*)(ab + (size_t)r0 * 256 + kn + c0);
        ra1 = *(const uint4*)(ab + (size_t)r1 * 256 + kn + c1);
        rb0 = *(const uint4*)(wb + (size_t)r0 * 256 + kn + c0);
        rb1 = *(const uint4*)(wb + (size_t)r1 * 256 + kn + c1);

#pragma unroll
        for (int kh = 0; kh < 2; ++kh) {
            bf16x8 af[2], bfg[2];
#pragma unroll
            for (int mi = 0; mi < 2; ++mi)
                af[mi]  = *(const bf16x8*)&As[(wm * 32 + mi * 16 + lq) * LSQ + kh * 32 + quad * 8];
#pragma unroll
            for (int ni = 0; ni < 2; ++ni)
                bfg[ni] = *(const bf16x8*)&Bs[(wn * 32 + ni * 16 + lq) * LSQ + kh * 32 + quad * 8];
#pragma unroll
            for (int ni = 0; ni < 2; ++ni)
#pragma unroll
                for (int mi = 0; mi < 2; ++mi)
                    acc[ni * 2 + mi] = __builtin_amdgcn_mfma_f32_16x16x32_bf16(
                        bfg[ni], af[mi], acc[ni * 2 + mi], 0, 0, 0);
        }
    }

#pragma unroll
    for (int ni = 0; ni < 2; ++ni) {
        int nb = n0 + wn * 32 + ni * 16 + quad * 4;
        float4 bs = *(const float4*)(bias + nb);
#pragma unroll
        for (int mi = 0; mi < 2; ++mi) {
            int m = m0 + wm * 32 + mi * 16 + lq;
            f32x4 c = acc[ni * 2 + mi];
            float4 o;
            o.x = c[0] + bs.x; o.y = c[1] + bs.y;
            o.z = c[2] + bs.z; o.w = c[3] + bs.w;
            *(float4*)&out[(size_t)m * DMODEL + nb] = o;
        }
    }
}

extern "C" void kernel_launch(void* const* d_in, const int* in_sizes, int n_in,
                              void* d_out, int out_size, void* d_ws, size_t ws_size,
                              hipStream_t stream) {
    const float* x     = (const float*)d_in[0];
    const float* w_qkv = (const float*)d_in[1];
    const float* b_qkv = (const float*)d_in[2];
    const float* w_out = (const float*)d_in[3];
    const float* b_out = (const float*)d_in[4];
    float* out = (float*)d_out;

    const size_t TSZ = (size_t)MTOT * DMODEL;
    ushort* q_ws = (ushort*)d_ws;          // Q pre-scaled bf16 [b,h,s,dh]
    ushort* k_ws = q_ws + TSZ;             // K bf16 [b,h,s,dh]
    ushort* v_ws = k_ws + TSZ;             // V^T bf16 [b,h,dh,s]
    ushort* a_bf = v_ws + TSZ;             // attn out bf16 [b,s,d]
    ushort* wqT  = a_bf + TSZ;
    ushort* woT  = wqT + 768 * 256;

    wcvt_all<<<dim3(32, 8), 256, 0, stream>>>(w_qkv, w_out, wqT, woT);
    qkv_gemm<<<dim3(6, 128), 256, 0, stream>>>(x, wqT, b_qkv, q_ws, k_ws, v_ws);
    attn_mfma<<<dim3(SEQ / 128, NH, BATCH), 512, 0, stream>>>(
        q_ws, k_ws, v_ws, a_bf);
    out_gemm<<<dim3(4, 128), 256, 0, stream>>>(a_bf, woT, b_out, out);
}

// Round 11
// 112.948 us; speedup vs baseline: 1.1883x; 1.0635x over previous
//
#include <hip/hip_runtime.h>
#include <hip/hip_bf16.h>
#include <math.h>

#define BATCH  4
#define SEQ    2048
#define DMODEL 256
#define NH     8
#define DH     32
#define MTOT   (BATCH*SEQ)   // 8192
// Q is pre-scaled by 256^-0.5 * log2(e) so attention uses p = exp2(q.k) raw.
#define QSCALE 0.09016844005556021f

typedef short  bf16x8 __attribute__((ext_vector_type(8)));
typedef float  f32x4  __attribute__((ext_vector_type(4)));

static __device__ __forceinline__ ushort f2bf(float f) {
    __hip_bfloat16 h = __float2bfloat16(f);
    return __builtin_bit_cast(ushort, h);
}
// RNE-pack two fp32 -> packed bf16x2 (low = a, high = b), software fallback.
static __device__ __forceinline__ uint rne2(float a, float b) {
    uint ua = __builtin_bit_cast(uint, a);
    uint ub = __builtin_bit_cast(uint, b);
    ua += 0x7FFFu + ((ua >> 16) & 1u);
    ub += 0x7FFFu + ((ub >> 16) & 1u);
    return __builtin_amdgcn_perm(ub, ua, 0x07060302);
}
// Packed bf16 convert: HW v_cvt_pk_bf16_f32 on gfx950 (1 op) else rne2.
static __device__ __forceinline__ uint pk2(float a, float b) {
#if __has_builtin(__builtin_amdgcn_cvt_pk_bf16_f32)
    auto r = __builtin_amdgcn_cvt_pk_bf16_f32(a, b);
    return __builtin_bit_cast(uint, r);
#else
    return rne2(a, b);
#endif
}

// exp2 -> packed bf16x2 of (a,b)
static __device__ __forceinline__ uint e2pk(float a, float b) {
    return pk2(__builtin_amdgcn_exp2f(a), __builtin_amdgcn_exp2f(b));
}

#define LSQ 72       // qkv/out LDS row stride (64 + 8 pad), ushorts
#define KS_STRIDE 40
#define VT_STRIDE 136

// ---------------------------------------------------------------------------
// Kernel 0: weight transposes + x fp32->bf16 conversion, ONE dispatch. (r3)
// ---------------------------------------------------------------------------
__global__ __launch_bounds__(256) void wcvt_all(
    const float* __restrict__ wq, const float* __restrict__ wo,
    const float* __restrict__ x,
    ushort* __restrict__ wqT, ushort* __restrict__ woT,
    ushort* __restrict__ xbf)
{
    const int t  = threadIdx.x;
    const int bx = blockIdx.x;
    if (bx >= 32) {
        const size_t base = ((size_t)(bx - 32) * 8 + blockIdx.y) * 4096 + t * 16;
        float4 f0 = *(const float4*)(x + base);
        float4 f1 = *(const float4*)(x + base + 4);
        float4 f2 = *(const float4*)(x + base + 8);
        float4 f3 = *(const float4*)(x + base + 12);
        uint4 w0, w1;
        w0.x = pk2(f0.x, f0.y); w0.y = pk2(f0.z, f0.w);
        w0.z = pk2(f1.x, f1.y); w0.w = pk2(f1.z, f1.w);
        w1.x = pk2(f2.x, f2.y); w1.y = pk2(f2.z, f2.w);
        w1.z = pk2(f3.x, f3.y); w1.w = pk2(f3.z, f3.w);
        *(uint4*)&xbf[base]     = w0;
        *(uint4*)&xbf[base + 8] = w1;
        return;
    }
    __shared__ float T[32][33];
    const float* w; ushort* wT; int N, n0;
    if (bx < 24) { w = wq; wT = wqT; N = 768; n0 = bx * 32; }
    else         { w = wo; wT = woT; N = 256; n0 = (bx - 24) * 32; }
    const int k0 = blockIdx.y * 32;
    {
        int tr = t >> 3, tc = (t & 7) * 4;
        *(float4*)&T[tr][tc] = *(const float4*)(w + (size_t)(k0 + tr) * N + n0 + tc);
    }
    __syncthreads();
    int nl = t >> 3, kq = (t & 7) * 4;
    ushort4 pk;
    pk.x = f2bf(T[kq + 0][nl]); pk.y = f2bf(T[kq + 1][nl]);
    pk.z = f2bf(T[kq + 2][nl]); pk.w = f2bf(T[kq + 3][nl]);
    *(ushort4*)&wT[(size_t)(n0 + nl) * 256 + k0 + kq] = pk;
}

// ---------------------------------------------------------------------------
// Kernel 1: QKV projection, bf16 MFMA, scalar reg-prefetch. (r8, proven)
// ---------------------------------------------------------------------------
__global__ __launch_bounds__(256, 3) void qkv_gemm(
    const ushort* __restrict__ xb_, const ushort* __restrict__ wT,
    const float* __restrict__ bias,
    ushort* __restrict__ qo, ushort* __restrict__ ko, ushort* __restrict__ vo)
{
    __shared__ ushort As[64 * LSQ];
    __shared__ ushort Bs[128 * LSQ];
    const int tid  = threadIdx.x;
    const int wid  = tid >> 6;
    const int lane = tid & 63;
    const int lq   = lane & 15;
    const int quad = lane >> 4;
    const int wm   = wid & 1;
    const int wn   = wid >> 1;
    const int m0   = blockIdx.y * 64;
    const int n0   = blockIdx.x * 128;
    const bool isV = (blockIdx.x >= 4);

    const int ar0 = tid >> 3,         ac0 = (tid & 7) * 8;
    const int ar1 = (tid + 256) >> 3;
    const int br0 = tid >> 3,         bc0 = (tid & 7) * 8;
    const int br1 = (tid + 256) >> 3;
    const int br2 = (tid + 512) >> 3;
    const int br3 = (tid + 768) >> 3;

    const ushort* xb = xb_ + (size_t)m0 * 256;
    const ushort* wb = wT  + (size_t)n0 * 256;

    f32x4 acc[8];
#pragma unroll
    for (int i = 0; i < 8; ++i) acc[i] = {0.f, 0.f, 0.f, 0.f};

    uint4 ra0 = *(const uint4*)(xb + (size_t)ar0 * 256 + ac0);
    uint4 ra1 = *(const uint4*)(xb + (size_t)ar1 * 256 + ac0);
    uint4 rb0 = *(const uint4*)(wb + (size_t)br0 * 256 + bc0);
    uint4 rb1 = *(const uint4*)(wb + (size_t)br1 * 256 + bc0);
    uint4 rb2 = *(const uint4*)(wb + (size_t)br2 * 256 + bc0);
    uint4 rb3 = *(const uint4*)(wb + (size_t)br3 * 256 + bc0);

    for (int k0 = 0; k0 < 256; k0 += 64) {
        __syncthreads();
        *(uint4*)&As[ar0 * LSQ + ac0] = ra0;
        *(uint4*)&As[ar1 * LSQ + ac0] = ra1;
        *(uint4*)&Bs[br0 * LSQ + bc0] = rb0;
        *(uint4*)&Bs[br1 * LSQ + bc0] = rb1;
        *(uint4*)&Bs[br2 * LSQ + bc0] = rb2;
        *(uint4*)&Bs[br3 * LSQ + bc0] = rb3;
        __syncthreads();

        const int kn = (k0 + 64) & 255;
        ra0 = *(const uint4*)(xb + (size_t)ar0 * 256 + kn + ac0);
        ra1 = *(const uint4*)(xb + (size_t)ar1 * 256 + kn + ac0);
        rb0 = *(const uint4*)(wb + (size_t)br0 * 256 + kn + bc0);
        rb1 = *(const uint4*)(wb + (size_t)br1 * 256 + kn + bc0);
        rb2 = *(const uint4*)(wb + (size_t)br2 * 256 + kn + bc0);
        rb3 = *(const uint4*)(wb + (size_t)br3 * 256 + kn + bc0);

#pragma unroll
        for (int kh = 0; kh < 2; ++kh) {
            bf16x8 af[2], bfg[4];
#pragma unroll
            for (int mi = 0; mi < 2; ++mi)
                af[mi]  = *(const bf16x8*)&As[(wm * 32 + mi * 16 + lq) * LSQ + kh * 32 + quad * 8];
#pragma unroll
            for (int ni = 0; ni < 4; ++ni)
                bfg[ni] = *(const bf16x8*)&Bs[(wn * 64 + ni * 16 + lq) * LSQ + kh * 32 + quad * 8];
            if (isV) {
#pragma unroll
                for (int mi = 0; mi < 2; ++mi)
#pragma unroll
                    for (int ni = 0; ni < 4; ++ni)
                        acc[mi * 4 + ni] = __builtin_amdgcn_mfma_f32_16x16x32_bf16(
                            af[mi], bfg[ni], acc[mi * 4 + ni], 0, 0, 0);
            } else {
#pragma unroll
                for (int ni = 0; ni < 4; ++ni)
#pragma unroll
                    for (int mi = 0; mi < 2; ++mi)
                        acc[ni * 2 + mi] = __builtin_amdgcn_mfma_f32_16x16x32_bf16(
                            bfg[ni], af[mi], acc[ni * 2 + mi], 0, 0, 0);
            }
        }
    }

    if (!isV) {
#pragma unroll
        for (int ni = 0; ni < 4; ++ni) {
            int nb = n0 + wn * 64 + ni * 16 + quad * 4;
            float4 bs = *(const float4*)(bias + nb);
            int h   = (nb >> 5) & 7;
            int dh0 = nb & 31;
            bool  isQ = (nb < 256);
            float sc  = isQ ? QSCALE : 1.0f;
            ushort* dst = isQ ? qo : ko;
#pragma unroll
            for (int mi = 0; mi < 2; ++mi) {
                int m   = m0 + wm * 32 + mi * 16 + lq;
                int b   = m >> 11, seq = m & 2047;
                f32x4 c = acc[ni * 2 + mi];
                ushort4 pk;
                pk.x = f2bf((c[0] + bs.x) * sc); pk.y = f2bf((c[1] + bs.y) * sc);
                pk.z = f2bf((c[2] + bs.z) * sc); pk.w = f2bf((c[3] + bs.w) * sc);
                *(ushort4*)&dst[(((size_t)b * NH + h) * SEQ + seq) * DH + dh0] = pk;
            }
        }
    } else {
#pragma unroll
        for (int ni = 0; ni < 4; ++ni) {
            int n  = n0 + wn * 64 + ni * 16 + lq;
            int h  = (n >> 5) & 7;
            int dh = n & 31;
            float bsc = bias[n];
#pragma unroll
            for (int mi = 0; mi < 2; ++mi) {
                int mb  = m0 + wm * 32 + mi * 16 + quad * 4;
                int b   = mb >> 11, seq = mb & 2047;
                f32x4 c = acc[mi * 4 + ni];
                ushort4 pk;
                pk.x = f2bf(c[0] + bsc); pk.y = f2bf(c[1] + bsc);
                pk.z = f2bf(c[2] + bsc); pk.w = f2bf(c[3] + bsc);
                *(ushort4*)&vo[(((size_t)b * NH + h) * DH + dh) * SEQ + seq] = pk;
            }
        }
    }
}

// ---------------------------------------------------------------------------
// Kernel 2: MFMA flash attention v10 = v6 (r3, best measured) + permuted
// K-staging that makes redist UNNECESSARY.
// The QK MFMA's A-row m comes from LDS slot (t*16+m); by staging K-row
// kr = s*32 + 8q + 4h + r  into slot  s*32 + 16h + 4q + r  (bijection,
// computed once), lane (lq,quad) after the two QK MFMAs holds
// S[32s+8*quad+0..3] (sa0) and S[32s+8*quad+4..7] (sa1) — so the packed
// exps ARE the PV B-frag directly.  Deletes 8 permlane ops + a 4-step
// serial chain per s-block (256 permlane/wave) in a latency-bound kernel.
// Values bit-identical to v6; only lane routing changed.
// ---------------------------------------------------------------------------
__global__ __launch_bounds__(512, 4) void attn_mfma(
    const ushort* __restrict__ qb, const ushort* __restrict__ kb,
    const ushort* __restrict__ vtb, ushort* __restrict__ a_bf)
{
    __shared__ ushort KsA[128 * KS_STRIDE];
    __shared__ ushort KsB[128 * KS_STRIDE];
    __shared__ ushort VsA[32 * VT_STRIDE];
    __shared__ ushort VsB[32 * VT_STRIDE];
    __shared__ float  Red[4][64][20];   // partner wave's O(16) + l0,l1

    const int tid  = threadIdx.x;
    const int wid  = tid >> 6;
    const int lane = tid & 63;
    const int lq   = lane & 15;
    const int quad = lane >> 4;
    const int half = wid >> 2;          // 0: even tiles, 1: odd tiles
    const int wq   = wid & 3;           // q-chunk within block

    // XCD-aware bijective swizzle: 512 blocks = 8 XCDs x 64; contiguous
    // work ids (sharing (b,h) K/V) land on one XCD's L2.
    const int lin = blockIdx.x + (blockIdx.y << 4) + (blockIdx.z << 7);
    const int swz = ((lin & 7) << 6) | (lin >> 3);
    const int h   = (swz >> 4) & 7;
    const int b   = swz >> 7;
    const int bh  = b * NH + h;
    const int q0  = (swz & 15) * 128 + wq * 32;

    const ushort* qbase = qb + ((size_t)bh * SEQ + q0) * DH;
    const bf16x8 qf0 = *(const bf16x8*)(qbase + (size_t)lq * DH + quad * 8);
    const bf16x8 qf1 = *(const bf16x8*)(qbase + (size_t)(16 + lq) * DH + quad * 8);

    const ushort* kbase  = kb  + (size_t)bh * SEQ * DH;
    const ushort* vtbase = vtb + (size_t)bh * DH * SEQ;

    const int kgo = (tid >> 2) * DH + (tid & 3) * 8;
    // permuted K-staging row: kr = [s(2b)][q(2b)][h(1b)][r(2b)] ->
    // slot = s*32 + h*16 + q*4 + r   (bijective within each 32-row group)
    const int kr  = tid >> 2;
    const int kpr = (kr & 0x60) | (((kr >> 2) & 1) << 4)
                  | (((kr >> 3) & 3) << 2) | (kr & 3);
    const int klo = kpr * KS_STRIDE + (tid & 3) * 8;
    const int vgo = (tid >> 4) * SEQ + (tid & 15) * 8;
    const int vlo = (tid >> 4) * VT_STRIDE + (tid & 15) * 8;

    uint4 krA = *(const uint4*)(kbase  + kgo);
    uint4 vrA = *(const uint4*)(vtbase + vgo);
    uint4 krB = *(const uint4*)(kbase  + 128 * DH + kgo);
    uint4 vrB = *(const uint4*)(vtbase + 128 + vgo);

    const ushort* Ksw = half ? KsB : KsA;
    const ushort* Vsw = half ? VsB : VsA;

    f32x4 o0 = {0.f,0.f,0.f,0.f}, o1 = {0.f,0.f,0.f,0.f};
    f32x4 o2 = {0.f,0.f,0.f,0.f}, o3 = {0.f,0.f,0.f,0.f};
    f32x4 la0 = {0.f,0.f,0.f,0.f}, la1 = {0.f,0.f,0.f,0.f};
    const bf16x8 ones = {0x3F80, 0x3F80, 0x3F80, 0x3F80,
                         0x3F80, 0x3F80, 0x3F80, 0x3F80};  // bf16(1.0) x8

    for (int kt = 0; kt < SEQ; kt += 256) {
        __syncthreads();
        *(uint4*)&KsA[klo] = krA;
        *(uint4*)&VsA[vlo] = vrA;
        *(uint4*)&KsB[klo] = krB;
        *(uint4*)&VsB[vlo] = vrB;
        __syncthreads();

        {   // unconditional prefetch (wraps on last iter; values unused)
            const int ka  = (kt + 256) & (SEQ - 1);
            const int kbn = (kt + 384) & (SEQ - 1);
            krA = *(const uint4*)(kbase  + (size_t)ka  * DH + kgo);
            vrA = *(const uint4*)(vtbase + ka  + vgo);
            krB = *(const uint4*)(kbase  + (size_t)kbn * DH + kgo);
            vrB = *(const uint4*)(vtbase + kbn + vgo);
        }

        // ---- per s-block: QK^T (4 MFMA) -> exp2/pack (direct B-frag) -> PV
#pragma unroll
        for (int s = 0; s < 4; ++s) {
            bf16x8 kf0 = *(const bf16x8*)&Ksw[((2*s    ) * 16 + lq) * KS_STRIDE + quad * 8];
            bf16x8 kf1 = *(const bf16x8*)&Ksw[((2*s + 1) * 16 + lq) * KS_STRIDE + quad * 8];
            f32x4 z = {0.f, 0.f, 0.f, 0.f};
            f32x4 sa0 = __builtin_amdgcn_mfma_f32_16x16x32_bf16(kf0, qf0, z, 0, 0, 0);
            f32x4 sa1 = __builtin_amdgcn_mfma_f32_16x16x32_bf16(kf1, qf0, z, 0, 0, 0);
            f32x4 sb0 = __builtin_amdgcn_mfma_f32_16x16x32_bf16(kf0, qf1, z, 0, 0, 0);
            f32x4 sb1 = __builtin_amdgcn_mfma_f32_16x16x32_bf16(kf1, qf1, z, 0, 0, 0);

            bf16x8 v0 = *(const bf16x8*)&Vsw[lq        * VT_STRIDE + s * 32 + quad * 8];
            bf16x8 v1 = *(const bf16x8*)&Vsw[(16 + lq) * VT_STRIDE + s * 32 + quad * 8];

            uint4 pw0 = {e2pk(sa0[0], sa0[1]), e2pk(sa0[2], sa0[3]),
                         e2pk(sa1[0], sa1[1]), e2pk(sa1[2], sa1[3])};
            uint4 pw1 = {e2pk(sb0[0], sb0[1]), e2pk(sb0[2], sb0[3]),
                         e2pk(sb1[0], sb1[1]), e2pk(sb1[2], sb1[3])};
            bf16x8 p0 = __builtin_bit_cast(bf16x8, pw0);
            bf16x8 p1 = __builtin_bit_cast(bf16x8, pw1);

            o0  = __builtin_amdgcn_mfma_f32_16x16x32_bf16(v0,   p0, o0,  0, 0, 0);
            o1  = __builtin_amdgcn_mfma_f32_16x16x32_bf16(v1,   p0, o1,  0, 0, 0);
            o2  = __builtin_amdgcn_mfma_f32_16x16x32_bf16(v0,   p1, o2,  0, 0, 0);
            o3  = __builtin_amdgcn_mfma_f32_16x16x32_bf16(v1,   p1, o3,  0, 0, 0);
            la0 = __builtin_amdgcn_mfma_f32_16x16x32_bf16(ones, p0, la0, 0, 0, 0);
            la1 = __builtin_amdgcn_mfma_f32_16x16x32_bf16(ones, p1, la1, 0, 0, 0);
        }
    }

    // ---- combine halves: O and l are plain sums (no-max softmax) ----
    __syncthreads();
    if (half) {
        float* r = &Red[wq][lane][0];
        r[0]  = o0[0]; r[1]  = o0[1]; r[2]  = o0[2]; r[3]  = o0[3];
        r[4]  = o1[0]; r[5]  = o1[1]; r[6]  = o1[2]; r[7]  = o1[3];
        r[8]  = o2[0]; r[9]  = o2[1]; r[10] = o2[2]; r[11] = o2[3];
        r[12] = o3[0]; r[13] = o3[1]; r[14] = o3[2]; r[15] = o3[3];
        r[16] = la0[0]; r[17] = la1[0];
    }
    __syncthreads();
    if (!half) {
        const float* r = &Red[wq][lane][0];
        o0[0] += r[0];  o0[1] += r[1];  o0[2] += r[2];  o0[3] += r[3];
        o1[0] += r[4];  o1[1] += r[5];  o1[2] += r[6];  o1[3] += r[7];
        o2[0] += r[8];  o2[1] += r[9];  o2[2] += r[10]; o2[3] += r[11];
        o3[0] += r[12]; o3[1] += r[13]; o3[2] += r[14]; o3[3] += r[15];
        float inv0 = 1.0f / (la0[0] + r[16]);
        float inv1 = 1.0f / (la1[0] + r[17]);

        ushort* dst0 = a_bf + ((size_t)b * SEQ + q0 + lq) * DMODEL + h * DH;
        ushort* dst1 = dst0 + 16 * DMODEL;
        uint2 w0, w1;
        w0.x = pk2(o0[0] * inv0, o0[1] * inv0);
        w0.y = pk2(o0[2] * inv0, o0[3] * inv0);
        w1.x = pk2(o1[0] * inv0, o1[1] * inv0);
        w1.y = pk2(o1[2] * inv0, o1[3] * inv0);
        *(uint2*)&dst0[quad * 4]      = w0;
        *(uint2*)&dst0[16 + quad * 4] = w1;
        w0.x = pk2(o2[0] * inv1, o2[1] * inv1);
        w0.y = pk2(o2[2] * inv1, o2[3] * inv1);
        w1.x = pk2(o3[0] * inv1, o3[1] * inv1);
        w1.y = pk2(o3[2] * inv1, o3[3] * inv1);
        *(uint2*)&dst1[quad * 4]      = w0;
        *(uint2*)&dst1[16 + quad * 4] = w1;
    }
}

// ---------------------------------------------------------------------------
// Kernel 3: out projection, bf16 MFMA, scalar reg-prefetch. (r8, proven)
// ---------------------------------------------------------------------------
__global__ __launch_bounds__(256) void out_gemm(
    const ushort* __restrict__ a, const ushort* __restrict__ wT,
    const float* __restrict__ bias, float* __restrict__ out)
{
    __shared__ ushort As[64 * LSQ];
    __shared__ ushort Bs[64 * LSQ];
    const int tid  = threadIdx.x;
    const int wid  = tid >> 6;
    const int lane = tid & 63;
    const int lq   = lane & 15;
    const int quad = lane >> 4;
    const int wm   = wid & 1;
    const int wn   = wid >> 1;
    const int m0   = blockIdx.y * 64;
    const int n0   = blockIdx.x * 64;

    const int f0 = tid, f1 = tid + 256;
    const int r0 = f0 >> 3, c0 = (f0 & 7) * 8;
    const int r1 = f1 >> 3, c1 = (f1 & 7) * 8;

    const ushort* ab = a  + (size_t)m0 * 256;
    const ushort* wb = wT + (size_t)n0 * 256;

    f32x4 acc[4];
#pragma unroll
    for (int i = 0; i < 4; ++i) acc[i] = {0.f, 0.f, 0.f, 0.f};

    uint4 ra0 = *(const uint4*)(ab + (size_t)r0 * 256 + c0);
    uint4 ra1 = *(const uint4*)(ab + (size_t)r1 * 256 + c1);
    uint4 rb0 = *(const uint4*)(wb + (size_t)r0 * 256 + c0);
    uint4 rb1 = *(const uint4*)(wb + (size_t)r1 * 256 + c1);

    for (int k0 = 0; k0 < 256; k0 += 64) {
        __syncthreads();
        *(uint4*)&As[r0 * LSQ + c0] = ra0;
        *(uint4*)&As[r1 * LSQ + c1] = ra1;
        *(uint4*)&Bs[r0 * LSQ + c0] = rb0;
        *(uint4*)&Bs[r1 * LSQ + c1] = rb1;
        __syncthreads();

        const int kn = (k0 + 64) & 255;
        ra0 = *(const uint4*)(ab + (size_t)r0 * 256 + kn + c0);
        ra1 = *(const uint4*)(ab + (size_t)r1 * 256 + kn + c1);
        rb0 = *(const uint4*)(wb + (size_t)r0 * 256 + kn + c0);
        rb1 = *(const uint4*)(wb + (size_t)r1 * 256 + kn + c1);

#pragma unroll
        for (int kh = 0; kh < 2; ++kh) {
            bf16x8 af[2], bfg[2];
#pragma unroll
            for (int mi = 0; mi < 2; ++mi)
                af[mi]  = *(const bf16x8*)&As[(wm * 32 + mi * 16 + lq) * LSQ + kh * 32 + quad * 8];
#pragma unroll
            for (int ni = 0; ni < 2; ++ni)
                bfg[ni] = *(const bf16x8*)&Bs[(wn * 32 + ni * 16 + lq) * LSQ + kh * 32 + quad * 8];
#pragma unroll
            for (int ni = 0; ni < 2; ++ni)
#pragma unroll
                for (int mi = 0; mi < 2; ++mi)
                    acc[ni * 2 + mi] = __builtin_amdgcn_mfma_f32_16x16x32_bf16(
                        bfg[ni], af[mi], acc[ni * 2 + mi], 0, 0, 0);
        }
    }

#pragma unroll
    for (int ni = 0; ni < 2; ++ni) {
        int nb = n0 + wn * 32 + ni * 16 + quad * 4;
        float4 bs = *(const float4*)(bias + nb);
#pragma unroll
        for (int mi = 0; mi < 2; ++mi) {
            int m = m0 + wm * 32 + mi * 16 + lq;
            f32x4 c = acc[ni * 2 + mi];
            float4 o;
            o.x = c[0] + bs.x; o.y = c[1] + bs.y;
            o.z = c[2] + bs.z; o.w = c[3] + bs.w;
            *(float4*)&out[(size_t)m * DMODEL + nb] = o;
        }
    }
}

extern "C" void kernel_launch(void* const* d_in, const int* in_sizes, int n_in,
                              void* d_out, int out_size, void* d_ws, size_t ws_size,
                              hipStream_t stream) {
    const float* x     = (const float*)d_in[0];
    const float* w_qkv = (const float*)d_in[1];
    const float* b_qkv = (const float*)d_in[2];
    const float* w_out = (const float*)d_in[3];
    const float* b_out = (const float*)d_in[4];
    float* out = (float*)d_out;

    const size_t TSZ = (size_t)MTOT * DMODEL;
    ushort* q_ws = (ushort*)d_ws;          // Q pre-scaled bf16 [b,h,s,dh]
    ushort* k_ws = q_ws + TSZ;             // K bf16 [b,h,s,dh]
    ushort* v_ws = k_ws + TSZ;             // V^T bf16 [b,h,dh,s]
    ushort* a_bf = v_ws + TSZ;             // attn out bf16 [b,s,d]
    ushort* xbf  = a_bf + TSZ;             // x bf16
    ushort* wqT  = xbf + TSZ;
    ushort* woT  = wqT + 768 * 256;

    wcvt_all<<<dim3(96, 8), 256, 0, stream>>>(w_qkv, w_out, x, wqT, woT, xbf);
    qkv_gemm<<<dim3(6, 128), 256, 0, stream>>>(xbf, wqT, b_qkv, q_ws, k_ws, v_ws);
    attn_mfma<<<dim3(SEQ / 128, NH, BATCH), 512, 0, stream>>>(
        q_ws, k_ws, v_ws, a_bf);
    out_gemm<<<dim3(4, 128), 256, 0, stream>>>(a_bf, woT, b_out, out);
}